// Round 11
// baseline (397.054 us; speedup 1.0000x reference)
//
#include <hip/hip_runtime.h>
#include <stdint.h>

// GaitnetActor B=8192, OPT=16. Round 28: FUSED persistent k_main.
// R27 post-mortem: setprio null (blocks in-phase -> m190 regime), conv-share
// neutral. Remaining us are inter-kernel / inter-round serialization.
// New structure: k_conv (404 blocks, R22 full conversion) + k_fused
// (512 blocks x 512 thr, persistent): each block computes se/cse ONCE at
// M=16 (exact k_cse geometry -> same 512x384KB weight traffic; R18's
// mistake was M=4 x 2048 blocks = 4x traffic), keeps cse[16][512] in LDS,
// then loops 4 chunks of the R26 unique+trunk pipeline (swapped MFMAs,
// in-reg heads, issue-early B loads, next-chunk obs prefetch).
// Deletes: k_cse launch, cse ws round-trip, per-round cse loads, 3 of 4
// block-round ramps. se-phase of block A overlaps trunk of block B.
// LDS 77056 B (overlays: h1u/h1s/seL/xs inside h1t region) -> 2 blocks/CU.
// out[0:131072]=logits fp32, [131072:262144]=duration fp32.

static constexpr int B_ = 8192;

typedef __attribute__((ext_vector_type(8))) short bf16x8;
typedef __attribute__((ext_vector_type(4))) float f32x4;

__device__ __forceinline__ float u2f(uint16_t u) {
    union { uint32_t i; float f; } c; c.i = (uint32_t)u << 16; return c.f;
}
__device__ __forceinline__ uint16_t f2u(float f) {
    __bf16 b = (__bf16)f;                       // native RNE cvt on gfx950
    return __builtin_bit_cast(uint16_t, b);
}
__device__ __forceinline__ ushort4 pack4(float a, float b, float c, float d) {
    ushort4 o;
    o.x = f2u(a); o.y = f2u(b); o.z = f2u(c); o.w = f2u(d);
    return o;
}

// ws layout (uint16 elems). WCSE region unused (cse lives in LDS now).
static constexpr size_t WTW1SE = 4194304;              // bf16 [512][256]
static constexpr size_t WTW1UE = WTW1SE + 131072;      // bf16 [512][128]
static constexpr size_t WTW2   = WTW1UE + 65536;       // bf16 [256][512]
static constexpr size_t WUW2   = WTW2 + 131072;        // bf16 [128][128]
static constexpr size_t WSW2   = WUW2 + 16384;         // bf16 [256][256]
static constexpr size_t WUW1B  = WSW2 + 65536;         // bf16 [128][32] 0-pad

// ---------------- k_conv: all weights fp32 -> bf16 (404 blocks) ------------
__global__ __launch_bounds__(256) void k_conv(
    const float* __restrict__ tw1, const float* __restrict__ tw2,
    const float* __restrict__ uw2, const float* __restrict__ sw2,
    const float* __restrict__ uw1, uint16_t* __restrict__ ws)
{
    int i4 = blockIdx.x * 256 + threadIdx.x;
    if (i4 >= 102400) {                          // uw1b: zero-padded K=32
        int q = i4 - 102400;                     // [0,1024)
        int n = q >> 3, k0 = (q & 7) * 4;
        ushort4 o = {0, 0, 0, 0};
        if (k0 < 8) {
            float4 v = *reinterpret_cast<const float4*>(uw1 + n * 8 + k0);
            o.x = f2u(v.x); o.y = f2u(v.y); o.z = f2u(v.z); o.w = f2u(v.w);
        }
        *reinterpret_cast<ushort4*>(ws + WUW1B + n * 32 + k0) = o;
        return;
    }
    const float* src; size_t dst;
    if (i4 < 32768) {                            // tw1 se-part (k<256)
        int g = i4 * 4, n = g >> 8, k = g & 255;
        src = tw1 + (size_t)n * 384 + k;
        dst = WTW1SE + (size_t)g;
    } else if (i4 < 49152) {                     // tw1 ue-part (k>=256)
        int q = i4 - 32768, n = q >> 5, w = q & 31;
        src = tw1 + (size_t)n * 384 + 256 + w * 4;
        dst = WTW1UE + (size_t)n * 128 + w * 4;
    } else if (i4 < 81920) {
        int q = (i4 - 49152) * 4;
        src = tw2 + q; dst = WTW2 + q;
    } else if (i4 < 86016) {
        int q = (i4 - 81920) * 4;
        src = uw2 + q; dst = WUW2 + q;
    } else {
        int q = (i4 - 86016) * 4;
        src = sw2 + q; dst = WSW2 + q;
    }
    float4 v = *reinterpret_cast<const float4*>(src);
    ushort4 o;
    o.x = f2u(v.x); o.y = f2u(v.y); o.z = f2u(v.z); o.w = f2u(v.w);
    *reinterpret_cast<ushort4*>(ws + dst) = o;
}

// ---------------- k_fused: se/cse (M=16, once) + 4 chunks of main ----------
// LDS (bytes), 77056 total -> 2 blocks/CU:
//   cseL bf16[16][512] @0 (16384, persists)
//   uet  bf16[64][136] @16384 (17408)
//   h1t  bf16[64][264] @33792 (33792); overlays (lifetime-disjoint):
//     h1u bf16[64][136] @33792 | se-phase: h1s bf16[16][264] @33792,
//     seL bf16[16][264] @42240, xs f32[16][24] @50688
//   uqb  bf16[64][40]  @67584 (5120)
//   noop f32[64]       @72704 (256)
//   hred f32[1024]     @72960 (4096)
static constexpr int CSE_OFF  = 0;
static constexpr int UET_OFF  = 16384;
static constexpr int H1T_OFF  = 33792;
static constexpr int H1U_OFF  = 33792;
static constexpr int H1S_OFF  = 33792;
static constexpr int SEL_OFF  = 42240;
static constexpr int XS_OFF   = 50688;
static constexpr int UQB_OFF  = 67584;
static constexpr int NOOP_OFF = 72704;
static constexpr int HRED_OFF = 72960;
static constexpr int SMEM_SZ  = 77056;

__global__ __launch_bounds__(512, 4) void k_fused(
    const float* __restrict__ obs,
    const float* __restrict__ sw1, const float* __restrict__ sb1,
    const float* __restrict__ sb2, const float* __restrict__ tb1,
    const float* __restrict__ ub1,
    const float* __restrict__ ub2, const float* __restrict__ emb,
    const float* __restrict__ tb2,
    const float* __restrict__ vw,  const float* __restrict__ vb,
    const float* __restrict__ dw,  const float* __restrict__ db,
    const uint16_t* __restrict__ wsb,
    float* __restrict__ out)
{
    __shared__ __align__(16) char smem[SMEM_SZ];
    uint16_t* cseL  = (uint16_t*)(smem + CSE_OFF);
    uint16_t* uet   = (uint16_t*)(smem + UET_OFF);
    uint16_t* h1t   = (uint16_t*)(smem + H1T_OFF);
    uint16_t* h1u   = (uint16_t*)(smem + H1U_OFF);
    uint16_t* h1s   = (uint16_t*)(smem + H1S_OFF);
    uint16_t* seL   = (uint16_t*)(smem + SEL_OFF);
    float*    xs    = (float*)(smem + XS_OFF);
    uint16_t* uqb   = (uint16_t*)(smem + UQB_OFF);
    float*    noopf = (float*)(smem + NOOP_OFF);
    float*    hred  = (float*)(smem + HRED_OFF);

    const int t    = threadIdx.x;
    const int wv   = t >> 6;
    const int lane = t & 63;
    const int quad = lane >> 4;
    const int l16  = lane & 15;
    const int bb16 = blockIdx.x * 16;            // block's 16 batch rows

    const uint16_t* tw1seb = wsb + WTW1SE;
    const uint16_t* tw1ue  = wsb + WTW1UE;
    const uint16_t* tw2b   = wsb + WTW2;
    const uint16_t* uw2b   = wsb + WUW2;
    const uint16_t* sw2b   = wsb + WSW2;
    const uint16_t* uw1b   = wsb + WUW1B;

    const int ur = t >> 3, uq = t & 7;           // uqb row 0..63, k-quad 0..7
    const int ue_ = ur >> 4, uo = ur & 15;

    // ================= se/cse phase (k_cse geometry, M=16) =================
    {
        if (t < 352) {
            int e = t / 22, c = t - e * 22;
            xs[e * 24 + c] = obs[(size_t)(bb16 + e) * 150 + c];
        }
        // chunk-0 uqb + noop
        ushort4 ov = {0, 0, 0, 0};
        if (uq < 2) {
            const float2* sp = reinterpret_cast<const float2*>(
                &obs[(size_t)(bb16 + ue_) * 150 + 22 + uo * 8 + uq * 4]);
            float2 a = sp[0], b = sp[1];
            ov.x = f2u(a.x); ov.y = f2u(a.y); ov.z = f2u(b.x); ov.w = f2u(b.y);
        }
        *reinterpret_cast<ushort4*>(&uqb[ur * 40 + uq * 4]) = ov;
        if (t < 64) {
            int ee = t >> 4, oo = t & 15;
            noopf[t] = (obs[(size_t)(bb16 + ee) * 150 + 22 + oo * 8] == 1.0f)
                           ? 1.0f : 0.0f;
        }
    }
    __syncthreads();
    // issue-early: se-L2 phase's first B pair (in flight through L1)
    const uint16_t* bb_se = sw2b + (size_t)(wv * 32 + l16) * 256 + quad * 8;
    bf16x8 seb0 = *reinterpret_cast<const bf16x8*>(bb_se);
    bf16x8 seb1 = *reinterpret_cast<const bf16x8*>(bb_se + 4096);
    {   // shared L1 (VALU): neuron t&255, 8 elems each
        const int n = t & 255;
        float w[22];
        #pragma unroll
        for (int k = 0; k < 22; ++k) w[k] = sw1[n * 22 + k];
        const float bias = sb1[n];
        #pragma unroll
        for (int ii = 0; ii < 8; ++ii) {
            int e = (t >> 8) * 8 + ii;
            float a = bias;
            #pragma unroll
            for (int k = 0; k < 22; ++k) a += w[k] * xs[e * 24 + k];
            h1s[e * 264 + n] = f2u(fmaxf(a, 0.f));
        }
    }
    __syncthreads();
    // issue-early: cse phase's first 4 B fragments (in flight through se-L2)
    const uint16_t* bb_c = tw1seb + (size_t)(wv * 64 + l16) * 256 + quad * 8;
    bf16x8 cseb[4];
    #pragma unroll
    for (int nt = 0; nt < 4; ++nt)
        cseb[nt] = *reinterpret_cast<const bf16x8*>(bb_c + nt * 4096);
    {   // shared L2 (MFMA): M=16, wave N=32, K=256 -> seL
        f32x4 acc[2];
        #pragma unroll
        for (int nt = 0; nt < 2; ++nt) {
            float bv = sb2[wv * 32 + nt * 16 + l16];
            acc[nt] = {bv, bv, bv, bv};
        }
        bf16x8 bc[2], bn[2];
        bc[0] = seb0; bc[1] = seb1;
        #pragma unroll
        for (int kk = 0; kk < 8; ++kk) {
            if (kk < 7) {
                bn[0] = *reinterpret_cast<const bf16x8*>(bb_se + (kk + 1) * 32);
                bn[1] = *reinterpret_cast<const bf16x8*>(bb_se + 4096 + (kk + 1) * 32);
            }
            bf16x8 af = *reinterpret_cast<const bf16x8*>(
                &h1s[l16 * 264 + kk * 32 + quad * 8]);
            #pragma unroll
            for (int nt = 0; nt < 2; ++nt)
                acc[nt] = __builtin_amdgcn_mfma_f32_16x16x32_bf16(
                    af, bc[nt], acc[nt], 0, 0, 0);
            bc[0] = bn[0]; bc[1] = bn[1];
        }
        #pragma unroll
        for (int nt = 0; nt < 2; ++nt)
            #pragma unroll
            for (int r = 0; r < 4; ++r)
                seL[(quad * 4 + r) * 264 + wv * 32 + nt * 16 + l16] =
                    f2u(fmaxf(acc[nt][r], 0.f));
    }
    __syncthreads();
    {   // cse (MFMA): M=16, wave N=64, K=256, no relu -> cseL (LDS)
        f32x4 acc[4];
        #pragma unroll
        for (int nt = 0; nt < 4; ++nt) {
            float bv = tb1[wv * 64 + nt * 16 + l16];
            acc[nt] = {bv, bv, bv, bv};
        }
        bf16x8 bc[4], bn[4];
        #pragma unroll
        for (int nt = 0; nt < 4; ++nt) bc[nt] = cseb[nt];
        #pragma unroll
        for (int kk = 0; kk < 8; ++kk) {
            if (kk < 7) {
                #pragma unroll
                for (int nt = 0; nt < 4; ++nt)
                    bn[nt] = *reinterpret_cast<const bf16x8*>(
                        bb_c + nt * 4096 + (kk + 1) * 32);
            }
            bf16x8 af = *reinterpret_cast<const bf16x8*>(
                &seL[l16 * 264 + kk * 32 + quad * 8]);
            #pragma unroll
            for (int nt = 0; nt < 4; ++nt)
                acc[nt] = __builtin_amdgcn_mfma_f32_16x16x32_bf16(
                    af, bc[nt], acc[nt], 0, 0, 0);
            #pragma unroll
            for (int nt = 0; nt < 4; ++nt) bc[nt] = bn[nt];
        }
        #pragma unroll
        for (int nt = 0; nt < 4; ++nt)
            #pragma unroll
            for (int r = 0; r < 4; ++r)
                cseL[(quad * 4 + r) * 512 + wv * 64 + nt * 16 + l16] =
                    f2u(acc[nt][r]);
    }
    __syncthreads();

    // ================= chunk loop: 4 x (unique + trunk + heads) ============
    const uint16_t* tw1ue_base = tw1ue + (size_t)(wv * 32 + l16) * 128 + quad * 8;
    bf16x8 wf2 = *reinterpret_cast<const bf16x8*>(
        &uw1b[(wv * 16 + l16) * 32 + quad * 8]);   // stage2 W (loop-invariant)

    #pragma unroll 1
    for (int c = 0; c < 4; ++c) {
        const int b0c = bb16 + c * 4;

        // ---- stage 2: unique L1, swapped mfma(W,X) -> b64 stores ----
        bf16x8 wf3;
        {
            float4 bv4 = *reinterpret_cast<const float4*>(&ub1[wv * 16 + quad * 4]);
            f32x4 acc[4];
            #pragma unroll
            for (int mt = 0; mt < 4; ++mt) acc[mt] = {bv4.x, bv4.y, bv4.z, bv4.w};
            #pragma unroll
            for (int mt = 0; mt < 4; ++mt) {
                bf16x8 xf = *reinterpret_cast<const bf16x8*>(
                    &uqb[(mt * 16 + l16) * 40 + quad * 8]);
                acc[mt] = __builtin_amdgcn_mfma_f32_16x16x32_bf16(wf2, xf, acc[mt], 0, 0, 0);
            }
            wf3 = *reinterpret_cast<const bf16x8*>(
                &uw2b[(size_t)(wv * 16 + l16) * 128 + quad * 8]);
            #pragma unroll
            for (int mt = 0; mt < 4; ++mt) {
                ushort4 o = pack4(fmaxf(acc[mt][0], 0.f), fmaxf(acc[mt][1], 0.f),
                                  fmaxf(acc[mt][2], 0.f), fmaxf(acc[mt][3], 0.f));
                *reinterpret_cast<ushort4*>(
                    &h1u[(mt * 16 + l16) * 136 + wv * 16 + quad * 4]) = o;
            }
        }
        __syncthreads();

        // ---- stage 3: unique L2, swapped, K=128 -> uet ----
        {
            float4 bv4 = *reinterpret_cast<const float4*>(&ub2[wv * 16 + quad * 4]);
            float4 ev4 = *reinterpret_cast<const float4*>(&emb[wv * 16 + quad * 4]);
            f32x4 acc[4];
            #pragma unroll
            for (int mt = 0; mt < 4; ++mt) acc[mt] = {bv4.x, bv4.y, bv4.z, bv4.w};
            bf16x8 wfc = wf3, wfn;
            #pragma unroll
            for (int kk = 0; kk < 4; ++kk) {
                if (kk < 3)
                    wfn = *reinterpret_cast<const bf16x8*>(
                        &uw2b[(size_t)(wv * 16 + l16) * 128 + (kk + 1) * 32 + quad * 8]);
                #pragma unroll
                for (int mt = 0; mt < 4; ++mt) {
                    bf16x8 xf = *reinterpret_cast<const bf16x8*>(
                        &h1u[(mt * 16 + l16) * 136 + kk * 32 + quad * 8]);
                    acc[mt] = __builtin_amdgcn_mfma_f32_16x16x32_bf16(wfc, xf, acc[mt], 0, 0, 0);
                }
                wfc = wfn;
            }
            #pragma unroll
            for (int mt = 0; mt < 4; ++mt) {
                bool noop = (noopf[mt * 16 + l16] != 0.0f);
                ushort4 o = pack4(noop ? ev4.x : fmaxf(acc[mt][0], 0.f),
                                  noop ? ev4.y : fmaxf(acc[mt][1], 0.f),
                                  noop ? ev4.z : fmaxf(acc[mt][2], 0.f),
                                  noop ? ev4.w : fmaxf(acc[mt][3], 0.f));
                *reinterpret_cast<ushort4*>(
                    &uet[(mt * 16 + l16) * 136 + wv * 16 + quad * 4]) = o;
            }
        }
        __syncthreads();

        // ---- trunk: prefetch next chunk's obs; 2 N-chunks of 256 ----
        float2 pf_a, pf_b; float pf_noop = 0.f;
        const bool havepf = (c < 3);
        if (havepf) {
            const int b0n = b0c + 4;
            if (uq < 2) {
                const float2* sp = reinterpret_cast<const float2*>(
                    &obs[(size_t)(b0n + ue_) * 150 + 22 + uo * 8 + uq * 4]);
                pf_a = sp[0]; pf_b = sp[1];
            }
            if (t < 64) {
                int ee = t >> 4, oo = t & 15;
                pf_noop = obs[(size_t)(b0n + ee) * 150 + 22 + oo * 8];
            }
        }

        f32x4 acc2[4][2];
        #pragma unroll
        for (int nt = 0; nt < 2; ++nt) {
            float4 bv4 = *reinterpret_cast<const float4*>(
                &tb2[wv * 32 + nt * 16 + quad * 4]);
            #pragma unroll
            for (int mt = 0; mt < 4; ++mt) acc2[mt][nt] = {bv4.x, bv4.y, bv4.z, bv4.w};
        }

        bf16x8 bc[2], bn[2];
        bc[0] = *reinterpret_cast<const bf16x8*>(tw1ue_base);
        bc[1] = *reinterpret_cast<const bf16x8*>(tw1ue_base + 2048);

        #pragma unroll
        for (int nc = 0; nc < 2; ++nc) {
            const uint16_t* bb = tw1ue_base + (size_t)nc * 32768;
            const uint16_t* cb = tw2b + (size_t)(wv * 32 + l16) * 512 + nc * 256
                                 + quad * 8;
            bf16x8 cc[2], cn[2];
            cc[0] = *reinterpret_cast<const bf16x8*>(cb);
            cc[1] = *reinterpret_cast<const bf16x8*>(cb + 8192);
            {
                f32x4 acc1[4][2];
                #pragma unroll
                for (int nt = 0; nt < 2; ++nt) {
                    int n0 = nc * 256 + wv * 32 + nt * 16 + quad * 4;
                    #pragma unroll
                    for (int mt = 0; mt < 4; ++mt) {
                        ushort4 cv = *reinterpret_cast<const ushort4*>(
                            &cseL[(c * 4 + mt) * 512 + n0]);
                        acc1[mt][nt] = {u2f(cv.x), u2f(cv.y), u2f(cv.z), u2f(cv.w)};
                    }
                }
                #pragma unroll
                for (int kk = 0; kk < 4; ++kk) {
                    if (kk < 3) {
                        bn[0] = *reinterpret_cast<const bf16x8*>(bb + (kk + 1) * 32);
                        bn[1] = *reinterpret_cast<const bf16x8*>(bb + 2048 + (kk + 1) * 32);
                    }
                    bf16x8 af[4];
                    #pragma unroll
                    for (int mt = 0; mt < 4; ++mt)
                        af[mt] = *reinterpret_cast<const bf16x8*>(
                            &uet[(mt * 16 + l16) * 136 + kk * 32 + quad * 8]);
                    #pragma unroll
                    for (int mt = 0; mt < 4; ++mt)
                        #pragma unroll
                        for (int nt = 0; nt < 2; ++nt)
                            acc1[mt][nt] = __builtin_amdgcn_mfma_f32_16x16x32_bf16(
                                bc[nt], af[mt], acc1[mt][nt], 0, 0, 0);
                    bc[0] = bn[0]; bc[1] = bn[1];
                }
                if (nc == 0) {  // issue-early: nc=1 L1 B
                    bc[0] = *reinterpret_cast<const bf16x8*>(tw1ue_base + 32768);
                    bc[1] = *reinterpret_cast<const bf16x8*>(tw1ue_base + 32768 + 2048);
                }
                #pragma unroll
                for (int mt = 0; mt < 4; ++mt)
                    #pragma unroll
                    for (int nt = 0; nt < 2; ++nt) {
                        ushort4 o = pack4(fmaxf(acc1[mt][nt][0], 0.f),
                                          fmaxf(acc1[mt][nt][1], 0.f),
                                          fmaxf(acc1[mt][nt][2], 0.f),
                                          fmaxf(acc1[mt][nt][3], 0.f));
                        *reinterpret_cast<ushort4*>(
                            &h1t[(mt * 16 + l16) * 264 + wv * 32 + nt * 16 + quad * 4]) = o;
                    }
            }
            __syncthreads();
            {
                #pragma unroll
                for (int k2 = 0; k2 < 8; ++k2) {
                    if (k2 < 7) {
                        cn[0] = *reinterpret_cast<const bf16x8*>(cb + (k2 + 1) * 32);
                        cn[1] = *reinterpret_cast<const bf16x8*>(cb + 8192 + (k2 + 1) * 32);
                    }
                    bf16x8 af[4];
                    #pragma unroll
                    for (int mt = 0; mt < 4; ++mt)
                        af[mt] = *reinterpret_cast<const bf16x8*>(
                            &h1t[(mt * 16 + l16) * 264 + k2 * 32 + quad * 8]);
                    #pragma unroll
                    for (int mt = 0; mt < 4; ++mt)
                        #pragma unroll
                        for (int nt = 0; nt < 2; ++nt)
                            acc2[mt][nt] = __builtin_amdgcn_mfma_f32_16x16x32_bf16(
                                cc[nt], af[mt], acc2[mt][nt], 0, 0, 0);
                    cc[0] = cn[0]; cc[1] = cn[1];
                }
            }
            if (nc == 0) __syncthreads();
        }
        __syncthreads();                         // last h1t read done

        // ---- heads (in-register) + next-chunk LDS staging ----
        {
            float svr[4] = {0.f, 0.f, 0.f, 0.f};
            float sdr[4] = {0.f, 0.f, 0.f, 0.f};
            #pragma unroll
            for (int nt = 0; nt < 2; ++nt) {
                float4 vw4 = *reinterpret_cast<const float4*>(
                    &vw[wv * 32 + nt * 16 + quad * 4]);
                float4 dw4 = *reinterpret_cast<const float4*>(
                    &dw[wv * 32 + nt * 16 + quad * 4]);
                #pragma unroll
                for (int mt = 0; mt < 4; ++mt) {
                    float t0 = fmaxf(acc2[mt][nt][0], 0.f);
                    float t1 = fmaxf(acc2[mt][nt][1], 0.f);
                    float t2v = fmaxf(acc2[mt][nt][2], 0.f);
                    float t3 = fmaxf(acc2[mt][nt][3], 0.f);
                    svr[mt] += t0 * vw4.x + t1 * vw4.y + t2v * vw4.z + t3 * vw4.w;
                    sdr[mt] += t0 * dw4.x + t1 * dw4.y + t2v * dw4.z + t3 * dw4.w;
                }
            }
            #pragma unroll
            for (int mt = 0; mt < 4; ++mt) {     // reduce over quads
                svr[mt] += __shfl_xor(svr[mt], 16);
                svr[mt] += __shfl_xor(svr[mt], 32);
                sdr[mt] += __shfl_xor(sdr[mt], 16);
                sdr[mt] += __shfl_xor(sdr[mt], 32);
            }
            if (quad == 0) {
                #pragma unroll
                for (int mt = 0; mt < 4; ++mt) {
                    int row = mt * 16 + l16;
                    hred[(row * 2 + 0) * 8 + wv] = svr[mt];
                    hred[(row * 2 + 1) * 8 + wv] = sdr[mt];
                }
            }
            if (havepf) {                        // stage next chunk's inputs
                ushort4 ov = {0, 0, 0, 0};
                if (uq < 2) {
                    ov.x = f2u(pf_a.x); ov.y = f2u(pf_a.y);
                    ov.z = f2u(pf_b.x); ov.w = f2u(pf_b.y);
                }
                *reinterpret_cast<ushort4*>(&uqb[ur * 40 + uq * 4]) = ov;
                if (t < 64) noopf[t] = (pf_noop == 1.0f) ? 1.0f : 0.0f;
            }
        }
        __syncthreads();
        if (t < 128) {                           // final reduce over 8 waves
            const float* p = &hred[t * 8];
            float s = p[0] + p[1] + p[2] + p[3] + p[4] + p[5] + p[6] + p[7];
            int row = t >> 1;
            int g = blockIdx.x * 256 + c * 64 + row;
            if ((t & 1) == 0) {
                out[g] = s + vb[0];
            } else {
                float z = s + db[0];
                float sig = 1.f / (1.f + __expf(-z));
                out[B_ * 16 + g] = sig * 0.4f + 0.1f;
            }
        }
    }
}

extern "C" void kernel_launch(void* const* d_in, const int* in_sizes, int n_in,
                              void* d_out, int out_size, void* d_ws, size_t ws_size,
                              hipStream_t stream) {
    const float* obs = (const float*)d_in[0];
    const float* sw1 = (const float*)d_in[1];
    const float* sb1 = (const float*)d_in[2];
    const float* sw2 = (const float*)d_in[3];
    const float* sb2 = (const float*)d_in[4];
    const float* uw1 = (const float*)d_in[5];
    const float* ub1 = (const float*)d_in[6];
    const float* uw2 = (const float*)d_in[7];
    const float* ub2 = (const float*)d_in[8];
    const float* emb = (const float*)d_in[9];
    const float* tw1 = (const float*)d_in[10];
    const float* tb1 = (const float*)d_in[11];
    const float* tw2 = (const float*)d_in[12];
    const float* tb2 = (const float*)d_in[13];
    const float* vw  = (const float*)d_in[14];
    const float* vb  = (const float*)d_in[15];
    const float* dw  = (const float*)d_in[16];
    const float* db  = (const float*)d_in[17];

    uint16_t* wsb = (uint16_t*)d_ws;

    k_conv<<<404, 256, 0, stream>>>(tw1, tw2, uw2, sw2, uw1, wsb);
    k_fused<<<B_ / 16, 512, 0, stream>>>(obs, sw1, sb1, sb2, tb1,
                                         ub1, ub2, emb, tb2,
                                         vw, vb, dw, db, wsb, (float*)d_out);
}

// Round 12
// 224.529 us; speedup vs baseline: 1.7684x; 1.7684x over previous
//
#include <hip/hip_runtime.h>
#include <stdint.h>

// GaitnetActor B=8192, OPT=16. Round 29: revert R28 fusion (spill disaster:
// WRITE 275MB scratch, occupancy collapse; lesson generalized: per-block
// weight reads are fixed ~416KB, so blocks x chunks multiplies L2 traffic --
// M=64 x 2048 blocks is the traffic optimum). Exact R26 restore (222.4us:
// swapped MFMAs, in-reg heads, deferred cse write, issue-early B loads)
// + micro-hoists: ub1/ub2/emb/tb2 bias vector loads issued one phase early
// (compiler can't hoist globals across __syncthreads).
// out[0:131072]=logits fp32, [131072:262144]=duration fp32.

static constexpr int B_ = 8192;

typedef __attribute__((ext_vector_type(8))) short bf16x8;
typedef __attribute__((ext_vector_type(4))) float f32x4;

__device__ __forceinline__ float u2f(uint16_t u) {
    union { uint32_t i; float f; } c; c.i = (uint32_t)u << 16; return c.f;
}
__device__ __forceinline__ uint16_t f2u(float f) {
    __bf16 b = (__bf16)f;                       // native RNE cvt on gfx950
    return __builtin_bit_cast(uint16_t, b);
}
__device__ __forceinline__ ushort4 pack4(float a, float b, float c, float d) {
    ushort4 o;
    o.x = f2u(a); o.y = f2u(b); o.z = f2u(c); o.w = f2u(d);
    return o;
}

// ws layout (uint16 elems)
static constexpr size_t WCSE   = 0;                    // bf16 [8192][512]
static constexpr size_t WTW1SE = 4194304;              // bf16 [512][256]
static constexpr size_t WTW1UE = WTW1SE + 131072;      // bf16 [512][128]
static constexpr size_t WTW2   = WTW1UE + 65536;       // bf16 [256][512]
static constexpr size_t WUW2   = WTW2 + 131072;        // bf16 [128][128]
static constexpr size_t WSW2   = WUW2 + 16384;         // bf16 [256][256]
static constexpr size_t WUW1B  = WSW2 + 65536;         // bf16 [128][32] 0-pad

// ---------------- k_conv: all weights fp32 -> bf16 (404 blocks) ------------
__global__ __launch_bounds__(256) void k_conv(
    const float* __restrict__ tw1, const float* __restrict__ tw2,
    const float* __restrict__ uw2, const float* __restrict__ sw2,
    const float* __restrict__ uw1, uint16_t* __restrict__ ws)
{
    int i4 = blockIdx.x * 256 + threadIdx.x;
    if (i4 >= 102400) {                          // uw1b: zero-padded K=32
        int q = i4 - 102400;                     // [0,1024)
        int n = q >> 3, k0 = (q & 7) * 4;
        ushort4 o = {0, 0, 0, 0};
        if (k0 < 8) {
            float4 v = *reinterpret_cast<const float4*>(uw1 + n * 8 + k0);
            o.x = f2u(v.x); o.y = f2u(v.y); o.z = f2u(v.z); o.w = f2u(v.w);
        }
        *reinterpret_cast<ushort4*>(ws + WUW1B + n * 32 + k0) = o;
        return;
    }
    const float* src; size_t dst;
    if (i4 < 32768) {                            // tw1 se-part (k<256)
        int g = i4 * 4, n = g >> 8, k = g & 255;
        src = tw1 + (size_t)n * 384 + k;
        dst = WTW1SE + (size_t)g;
    } else if (i4 < 49152) {                     // tw1 ue-part (k>=256)
        int q = i4 - 32768, n = q >> 5, w = q & 31;
        src = tw1 + (size_t)n * 384 + 256 + w * 4;
        dst = WTW1UE + (size_t)n * 128 + w * 4;
    } else if (i4 < 81920) {
        int q = (i4 - 49152) * 4;
        src = tw2 + q; dst = WTW2 + q;
    } else if (i4 < 86016) {
        int q = (i4 - 81920) * 4;
        src = uw2 + q; dst = WUW2 + q;
    } else {
        int q = (i4 - 86016) * 4;
        src = sw2 + q; dst = WSW2 + q;
    }
    float4 v = *reinterpret_cast<const float4*>(src);
    ushort4 o;
    o.x = f2u(v.x); o.y = f2u(v.y); o.z = f2u(v.z); o.w = f2u(v.w);
    *reinterpret_cast<ushort4*>(ws + dst) = o;
}

// ---------------- k_cse: se + cse, 16 elems/block, 512 thr (512 blocks) ----
__global__ __launch_bounds__(512) void k_cse(
    const float* __restrict__ obs,
    const float* __restrict__ sw1, const float* __restrict__ sb1,
    const float* __restrict__ sb2, const float* __restrict__ tb1,
    uint16_t* __restrict__ ws)
{
    __shared__ float xs[16][24];
    __shared__ uint16_t h1s[16 * 264];
    __shared__ uint16_t seL[16 * 264];
    const int t = threadIdx.x;
    const int b0 = blockIdx.x * 16;
    const int wv = t >> 6, lane = t & 63, quad = lane >> 4, l16 = lane & 15;
    const uint16_t* sw2b   = ws + WSW2;
    const uint16_t* tw1seb = ws + WTW1SE;

    if (t < 352) {
        int e = t / 22, c = t - e * 22;
        xs[e][c] = obs[(size_t)(b0 + e) * 150 + c];
    }
    __syncthreads();
    // issue-early: shared-L2 phase's first B pair (in flight through L1)
    const uint16_t* bb_se = sw2b + (size_t)(wv * 32 + l16) * 256 + quad * 8;
    bf16x8 seb0 = *reinterpret_cast<const bf16x8*>(bb_se);
    bf16x8 seb1 = *reinterpret_cast<const bf16x8*>(bb_se + 4096);
    {   // shared L1 (VALU): neuron t&255, 8 elems each
        const int n = t & 255;
        float w[22];
        #pragma unroll
        for (int k = 0; k < 22; ++k) w[k] = sw1[n * 22 + k];
        const float bias = sb1[n];
        #pragma unroll
        for (int ii = 0; ii < 8; ++ii) {
            int e = (t >> 8) * 8 + ii;
            float a = bias;
            #pragma unroll
            for (int k = 0; k < 22; ++k) a += w[k] * xs[e][k];
            h1s[e * 264 + n] = f2u(fmaxf(a, 0.f));
        }
    }
    __syncthreads();
    // issue-early: cse phase's first 4 B fragments (in flight through se-L2)
    const uint16_t* bb_c = tw1seb + (size_t)(wv * 64 + l16) * 256 + quad * 8;
    bf16x8 cseb[4];
    #pragma unroll
    for (int nt = 0; nt < 4; ++nt)
        cseb[nt] = *reinterpret_cast<const bf16x8*>(bb_c + nt * 4096);
    {   // shared L2 (MFMA): M=16, wave N=32, K=256 -> seL
        f32x4 acc[2];
        #pragma unroll
        for (int nt = 0; nt < 2; ++nt) {
            float bv = sb2[wv * 32 + nt * 16 + l16];
            acc[nt] = {bv, bv, bv, bv};
        }
        bf16x8 bc[2], bn[2];
        bc[0] = seb0; bc[1] = seb1;
        #pragma unroll
        for (int kk = 0; kk < 8; ++kk) {
            if (kk < 7) {
                bn[0] = *reinterpret_cast<const bf16x8*>(bb_se + (kk + 1) * 32);
                bn[1] = *reinterpret_cast<const bf16x8*>(bb_se + 4096 + (kk + 1) * 32);
            }
            bf16x8 af = *reinterpret_cast<const bf16x8*>(
                &h1s[l16 * 264 + kk * 32 + quad * 8]);
            #pragma unroll
            for (int nt = 0; nt < 2; ++nt)
                acc[nt] = __builtin_amdgcn_mfma_f32_16x16x32_bf16(
                    af, bc[nt], acc[nt], 0, 0, 0);
            bc[0] = bn[0]; bc[1] = bn[1];
        }
        #pragma unroll
        for (int nt = 0; nt < 2; ++nt)
            #pragma unroll
            for (int r = 0; r < 4; ++r)
                seL[(quad * 4 + r) * 264 + wv * 32 + nt * 16 + l16] =
                    f2u(fmaxf(acc[nt][r], 0.f));
    }
    __syncthreads();
    {   // cse (MFMA): M=16, wave N=64, K=256, no relu -> ws
        f32x4 acc[4];
        #pragma unroll
        for (int nt = 0; nt < 4; ++nt) {
            float bv = tb1[wv * 64 + nt * 16 + l16];
            acc[nt] = {bv, bv, bv, bv};
        }
        bf16x8 bc[4], bn[4];
        #pragma unroll
        for (int nt = 0; nt < 4; ++nt) bc[nt] = cseb[nt];
        #pragma unroll
        for (int kk = 0; kk < 8; ++kk) {
            if (kk < 7) {
                #pragma unroll
                for (int nt = 0; nt < 4; ++nt)
                    bn[nt] = *reinterpret_cast<const bf16x8*>(
                        bb_c + nt * 4096 + (kk + 1) * 32);
            }
            bf16x8 af = *reinterpret_cast<const bf16x8*>(
                &seL[l16 * 264 + kk * 32 + quad * 8]);
            #pragma unroll
            for (int nt = 0; nt < 4; ++nt)
                acc[nt] = __builtin_amdgcn_mfma_f32_16x16x32_bf16(
                    af, bc[nt], acc[nt], 0, 0, 0);
            #pragma unroll
            for (int nt = 0; nt < 4; ++nt) bc[nt] = bn[nt];
        }
        #pragma unroll
        for (int nt = 0; nt < 4; ++nt)
            #pragma unroll
            for (int r = 0; r < 4; ++r)
                ws[WCSE + (size_t)(b0 + quad * 4 + r) * 512 +
                   wv * 64 + nt * 16 + l16] = f2u(acc[nt][r]);
    }
}

// ---- k_main (swapped MFMAs, in-reg heads, deferred cse, issue-early) ------
// LDS (bytes): uqb bf16[64][40] 0..5120 | noop f32[64] @5120 | cse bf16[4][512]
// @5376 | h1u bf16[64][136] @9472 | uet @26880 | h1t bf16[64][264] @44288
// (hred f32[1024] overlays h1t after trunk) -> 78080 B, 2 blocks/CU.
static constexpr int UQB_OFF  = 0;
static constexpr int NOOP_OFF = 5120;
static constexpr int CSE_OFF  = 5376;
static constexpr int H1U_OFF  = 9472;
static constexpr int UET_OFF  = 26880;
static constexpr int H1T_OFF  = 44288;
static constexpr int SMEM_SZ  = 78080;

__global__ __launch_bounds__(512, 4) void k_main(
    const float* __restrict__ obs,
    const float* __restrict__ ub1,
    const float* __restrict__ ub2, const float* __restrict__ emb,
    const float* __restrict__ tb2,
    const float* __restrict__ vw,  const float* __restrict__ vb,
    const float* __restrict__ dw,  const float* __restrict__ db,
    const uint16_t* __restrict__ wsb,
    float* __restrict__ out)
{
    __shared__ __align__(16) char smem[SMEM_SZ];
    uint16_t* uqb   = (uint16_t*)(smem + UQB_OFF);
    float*    noopf = (float*)(smem + NOOP_OFF);
    uint16_t* cseL  = (uint16_t*)(smem + CSE_OFF);
    uint16_t* h1u   = (uint16_t*)(smem + H1U_OFF);
    uint16_t* uet   = (uint16_t*)(smem + UET_OFF);
    uint16_t* h1t   = (uint16_t*)(smem + H1T_OFF);
    float*    hred  = (float*)(smem + H1T_OFF);

    const int t    = threadIdx.x;
    const int wv   = t >> 6;
    const int lane = t & 63;
    const int quad = lane >> 4;
    const int l16  = lane & 15;
    const int b0   = blockIdx.x * 4;

    const uint16_t* csep  = wsb + WCSE;
    const uint16_t* tw1ue = wsb + WTW1UE;
    const uint16_t* tw2b  = wsb + WTW2;
    const uint16_t* uw2b  = wsb + WUW2;
    const uint16_t* uw1b  = wsb + WUW1B;

    // ---- stage 1: uqb bf16 [64][40] (K=32 zero-padded), noop; cse -> regs --
    uint32_t cse_r0, cse_r1;
    bf16x8 wf2;                                  // stage2 W (issue-early)
    float4 bv1_4;                                // stage2 bias (issue-early)
    {
        int r = t >> 3, q = t & 7;               // row 0..63, k-quad 0..7
        int e = r >> 4, o = r & 15;
        ushort4 ov = {0, 0, 0, 0};
        if (q < 2) {                             // cols 0..7 real (8B-aligned)
            const float2* sp = reinterpret_cast<const float2*>(
                &obs[(size_t)(b0 + e) * 150 + 22 + o * 8 + q * 4]);
            float2 a = sp[0], b = sp[1];
            ov.x = f2u(a.x); ov.y = f2u(a.y); ov.z = f2u(b.x); ov.w = f2u(b.y);
        }
        *reinterpret_cast<ushort4*>(&uqb[r * 40 + q * 4]) = ov;
        const uint32_t* cp = (const uint32_t*)(csep + (size_t)b0 * 512);
        cse_r0 = cp[t];
        cse_r1 = cp[t + 512];
        wf2 = *reinterpret_cast<const bf16x8*>(
            &uw1b[(wv * 16 + l16) * 32 + quad * 8]);
        bv1_4 = *reinterpret_cast<const float4*>(&ub1[wv * 16 + quad * 4]);
        if (t < 64) {
            int ee = t >> 4, oo = t & 15;
            noopf[t] = (obs[(size_t)(b0 + ee) * 150 + 22 + oo * 8] == 1.0f) ? 1.0f : 0.0f;
        }
    }
    __syncthreads();

    // ---- stage 2: unique L1, swapped mfma(W,X) -> b64 stores ----
    bf16x8 wf3;                                  // stage3 kk=0 W (issue-early)
    float4 bv2_4, ev_4;                          // stage3 bias/emb (issue-early)
    {
        f32x4 acc[4];
        #pragma unroll
        for (int mt = 0; mt < 4; ++mt) acc[mt] = {bv1_4.x, bv1_4.y, bv1_4.z, bv1_4.w};
        #pragma unroll
        for (int mt = 0; mt < 4; ++mt) {
            bf16x8 xf = *reinterpret_cast<const bf16x8*>(
                &uqb[(mt * 16 + l16) * 40 + quad * 8]);
            acc[mt] = __builtin_amdgcn_mfma_f32_16x16x32_bf16(wf2, xf, acc[mt], 0, 0, 0);
        }
        wf3 = *reinterpret_cast<const bf16x8*>(
            &uw2b[(size_t)(wv * 16 + l16) * 128 + quad * 8]);
        bv2_4 = *reinterpret_cast<const float4*>(&ub2[wv * 16 + quad * 4]);
        ev_4  = *reinterpret_cast<const float4*>(&emb[wv * 16 + quad * 4]);
        #pragma unroll
        for (int mt = 0; mt < 4; ++mt) {
            ushort4 o = pack4(fmaxf(acc[mt][0], 0.f), fmaxf(acc[mt][1], 0.f),
                              fmaxf(acc[mt][2], 0.f), fmaxf(acc[mt][3], 0.f));
            *reinterpret_cast<ushort4*>(
                &h1u[(mt * 16 + l16) * 136 + wv * 16 + quad * 4]) = o;
        }
    }
    __syncthreads();

    // ---- stage 3: unique L2, swapped, K=128 -> uet (b64 stores) ----
    float4 tb2_4[2];                             // trunk bias (issue-early)
    {
        f32x4 acc[4];
        #pragma unroll
        for (int mt = 0; mt < 4; ++mt) acc[mt] = {bv2_4.x, bv2_4.y, bv2_4.z, bv2_4.w};
        bf16x8 wfc = wf3, wfn;
        #pragma unroll
        for (int kk = 0; kk < 4; ++kk) {
            if (kk < 3)
                wfn = *reinterpret_cast<const bf16x8*>(
                    &uw2b[(size_t)(wv * 16 + l16) * 128 + (kk + 1) * 32 + quad * 8]);
            #pragma unroll
            for (int mt = 0; mt < 4; ++mt) {
                bf16x8 xf = *reinterpret_cast<const bf16x8*>(
                    &h1u[(mt * 16 + l16) * 136 + kk * 32 + quad * 8]);
                acc[mt] = __builtin_amdgcn_mfma_f32_16x16x32_bf16(wfc, xf, acc[mt], 0, 0, 0);
            }
            wfc = wfn;
        }
        #pragma unroll
        for (int nt = 0; nt < 2; ++nt)
            tb2_4[nt] = *reinterpret_cast<const float4*>(
                &tb2[wv * 32 + nt * 16 + quad * 4]);
        #pragma unroll
        for (int mt = 0; mt < 4; ++mt) {
            bool noop = (noopf[mt * 16 + l16] != 0.0f);
            ushort4 o = pack4(noop ? ev_4.x : fmaxf(acc[mt][0], 0.f),
                              noop ? ev_4.y : fmaxf(acc[mt][1], 0.f),
                              noop ? ev_4.z : fmaxf(acc[mt][2], 0.f),
                              noop ? ev_4.w : fmaxf(acc[mt][3], 0.f));
            *reinterpret_cast<ushort4*>(
                &uet[(mt * 16 + l16) * 136 + wv * 16 + quad * 4]) = o;
        }
        // deferred cse LDS write (loads issued in stage 1, latency hidden)
        ((uint32_t*)cseL)[t] = cse_r0;
        ((uint32_t*)cseL)[t + 512] = cse_r1;
    }
    __syncthreads();

    // ---- trunk: 2 N-chunks of 256; swapped L1 (acc init = cse) -> L2 ----
    f32x4 acc2[4][2];
    #pragma unroll
    for (int nt = 0; nt < 2; ++nt) {
        #pragma unroll
        for (int mt = 0; mt < 4; ++mt)
            acc2[mt][nt] = {tb2_4[nt].x, tb2_4[nt].y, tb2_4[nt].z, tb2_4[nt].w};
    }

    const uint16_t* tw1ue_base = tw1ue + (size_t)(wv * 32 + l16) * 128 + quad * 8;
    bf16x8 bc[2], bn[2];
    bc[0] = *reinterpret_cast<const bf16x8*>(tw1ue_base);
    bc[1] = *reinterpret_cast<const bf16x8*>(tw1ue_base + 2048);

    #pragma unroll
    for (int nc = 0; nc < 2; ++nc) {
        const uint16_t* bb = tw1ue_base + (size_t)nc * 32768;
        const uint16_t* cb = tw2b + (size_t)(wv * 32 + l16) * 512 + nc * 256
                             + quad * 8;
        // issue-early: this nc's L2-phase B (in flight through L1 phase)
        bf16x8 cc[2], cn[2];
        cc[0] = *reinterpret_cast<const bf16x8*>(cb);
        cc[1] = *reinterpret_cast<const bf16x8*>(cb + 8192);
        {
            f32x4 acc1[4][2];
            #pragma unroll
            for (int nt = 0; nt < 2; ++nt) {
                int n0 = nc * 256 + wv * 32 + nt * 16 + quad * 4;
                #pragma unroll
                for (int mt = 0; mt < 4; ++mt) {
                    ushort4 cv = *reinterpret_cast<const ushort4*>(
                        &cseL[mt * 512 + n0]);
                    acc1[mt][nt] = {u2f(cv.x), u2f(cv.y), u2f(cv.z), u2f(cv.w)};
                }
            }
            #pragma unroll
            for (int kk = 0; kk < 4; ++kk) {
                if (kk < 3) {
                    bn[0] = *reinterpret_cast<const bf16x8*>(bb + (kk + 1) * 32);
                    bn[1] = *reinterpret_cast<const bf16x8*>(bb + 2048 + (kk + 1) * 32);
                }
                bf16x8 af[4];
                #pragma unroll
                for (int mt = 0; mt < 4; ++mt)
                    af[mt] = *reinterpret_cast<const bf16x8*>(
                        &uet[(mt * 16 + l16) * 136 + kk * 32 + quad * 8]);
                #pragma unroll
                for (int mt = 0; mt < 4; ++mt)
                    #pragma unroll
                    for (int nt = 0; nt < 2; ++nt)
                        acc1[mt][nt] = __builtin_amdgcn_mfma_f32_16x16x32_bf16(
                            bc[nt], af[mt], acc1[mt][nt], 0, 0, 0);
                bc[0] = bn[0]; bc[1] = bn[1];
            }
            if (nc == 0) {   // issue-early: nc=1 L1 B (in flight through L2)
                bc[0] = *reinterpret_cast<const bf16x8*>(tw1ue_base + 32768);
                bc[1] = *reinterpret_cast<const bf16x8*>(tw1ue_base + 32768 + 2048);
            }
            #pragma unroll
            for (int mt = 0; mt < 4; ++mt)
                #pragma unroll
                for (int nt = 0; nt < 2; ++nt) {
                    ushort4 o = pack4(fmaxf(acc1[mt][nt][0], 0.f),
                                      fmaxf(acc1[mt][nt][1], 0.f),
                                      fmaxf(acc1[mt][nt][2], 0.f),
                                      fmaxf(acc1[mt][nt][3], 0.f));
                    *reinterpret_cast<ushort4*>(
                        &h1t[(mt * 16 + l16) * 264 + wv * 32 + nt * 16 + quad * 4]) = o;
                }
        }
        __syncthreads();
        {
            #pragma unroll
            for (int k2 = 0; k2 < 8; ++k2) {
                if (k2 < 7) {
                    cn[0] = *reinterpret_cast<const bf16x8*>(cb + (k2 + 1) * 32);
                    cn[1] = *reinterpret_cast<const bf16x8*>(cb + 8192 + (k2 + 1) * 32);
                }
                bf16x8 af[4];
                #pragma unroll
                for (int mt = 0; mt < 4; ++mt)
                    af[mt] = *reinterpret_cast<const bf16x8*>(
                        &h1t[(mt * 16 + l16) * 264 + k2 * 32 + quad * 8]);
                #pragma unroll
                for (int mt = 0; mt < 4; ++mt)
                    #pragma unroll
                    for (int nt = 0; nt < 2; ++nt)
                        acc2[mt][nt] = __builtin_amdgcn_mfma_f32_16x16x32_bf16(
                            cc[nt], af[mt], acc2[mt][nt], 0, 0, 0);
                cc[0] = cn[0]; cc[1] = cn[1];
            }
        }
        if (nc == 0) __syncthreads();
    }
    __syncthreads();                             // last h1t read done

    // ---- heads: in-register from acc2 (fp32 t, no bf16 round) ----
    {
        float svr[4] = {0.f, 0.f, 0.f, 0.f};
        float sdr[4] = {0.f, 0.f, 0.f, 0.f};
        #pragma unroll
        for (int nt = 0; nt < 2; ++nt) {
            float4 vw4 = *reinterpret_cast<const float4*>(
                &vw[wv * 32 + nt * 16 + quad * 4]);
            float4 dw4 = *reinterpret_cast<const float4*>(
                &dw[wv * 32 + nt * 16 + quad * 4]);
            #pragma unroll
            for (int mt = 0; mt < 4; ++mt) {
                float t0 = fmaxf(acc2[mt][nt][0], 0.f);
                float t1 = fmaxf(acc2[mt][nt][1], 0.f);
                float t2 = fmaxf(acc2[mt][nt][2], 0.f);
                float t3 = fmaxf(acc2[mt][nt][3], 0.f);
                svr[mt] += t0 * vw4.x + t1 * vw4.y + t2 * vw4.z + t3 * vw4.w;
                sdr[mt] += t0 * dw4.x + t1 * dw4.y + t2 * dw4.z + t3 * dw4.w;
            }
        }
        #pragma unroll
        for (int mt = 0; mt < 4; ++mt) {         // reduce over quads
            svr[mt] += __shfl_xor(svr[mt], 16);
            svr[mt] += __shfl_xor(svr[mt], 32);
            sdr[mt] += __shfl_xor(sdr[mt], 16);
            sdr[mt] += __shfl_xor(sdr[mt], 32);
        }
        if (quad == 0) {                         // stage per-wave partials
            #pragma unroll
            for (int mt = 0; mt < 4; ++mt) {
                int row = mt * 16 + l16;
                hred[(row * 2 + 0) * 8 + wv] = svr[mt];
                hred[(row * 2 + 1) * 8 + wv] = sdr[mt];
            }
        }
    }
    __syncthreads();
    if (t < 128) {                               // final reduce over 8 waves
        const float* p = &hred[t * 8];
        float s = p[0] + p[1] + p[2] + p[3] + p[4] + p[5] + p[6] + p[7];
        int row = t >> 1;
        int g = blockIdx.x * 64 + row;
        if ((t & 1) == 0) {
            out[g] = s + vb[0];
        } else {
            float z = s + db[0];
            float sig = 1.f / (1.f + __expf(-z));
            out[B_ * 16 + g] = sig * 0.4f + 0.1f;
        }
    }
}

extern "C" void kernel_launch(void* const* d_in, const int* in_sizes, int n_in,
                              void* d_out, int out_size, void* d_ws, size_t ws_size,
                              hipStream_t stream) {
    const float* obs = (const float*)d_in[0];
    const float* sw1 = (const float*)d_in[1];
    const float* sb1 = (const float*)d_in[2];
    const float* sw2 = (const float*)d_in[3];
    const float* sb2 = (const float*)d_in[4];
    const float* uw1 = (const float*)d_in[5];
    const float* ub1 = (const float*)d_in[6];
    const float* uw2 = (const float*)d_in[7];
    const float* ub2 = (const float*)d_in[8];
    const float* emb = (const float*)d_in[9];
    const float* tw1 = (const float*)d_in[10];
    const float* tb1 = (const float*)d_in[11];
    const float* tw2 = (const float*)d_in[12];
    const float* tb2 = (const float*)d_in[13];
    const float* vw  = (const float*)d_in[14];
    const float* vb  = (const float*)d_in[15];
    const float* dw  = (const float*)d_in[16];
    const float* db  = (const float*)d_in[17];

    uint16_t* wsb = (uint16_t*)d_ws;

    k_conv<<<404, 256, 0, stream>>>(tw1, tw2, uw2, sw2, uw1, wsb);
    k_cse<<<512, 512, 0, stream>>>(obs, sw1, sb1, sb2, tb1, wsb);
    k_main<<<B_ / 4, 512, 0, stream>>>(obs, ub1, ub2, emb, tb2,
                                       vw, vb, dw, db, wsb, (float*)d_out);
}

// Round 13
// 224.209 us; speedup vs baseline: 1.7709x; 1.0014x over previous
//
#include <hip/hip_runtime.h>
#include <stdint.h>

// GaitnetActor B=8192, OPT=16. Round 30: R29 base (k_main 118.0us best;
// swapped MFMAs, in-reg heads, deferred cse write, issue-early B+bias).
// New: DEPTH-2 software pipelining on every B-stream loop at ZERO register
// cost -- rotate the existing current/next fragment pair as a 2-slot
// buffer (preload kk=0,1; in iter kk reload slot kk&1 with kk+2). Doubles
// load-latency cover (~100 -> ~200cy of ~300cy L2 latency) in: k_cse se-L2
// + cse phases, k_main stage-3 W chain, trunk L1 (4 it), trunk L2 (8 it).
// Pure reschedule, bit-identical numerics.
// out[0:131072]=logits fp32, [131072:262144]=duration fp32.

static constexpr int B_ = 8192;

typedef __attribute__((ext_vector_type(8))) short bf16x8;
typedef __attribute__((ext_vector_type(4))) float f32x4;

__device__ __forceinline__ float u2f(uint16_t u) {
    union { uint32_t i; float f; } c; c.i = (uint32_t)u << 16; return c.f;
}
__device__ __forceinline__ uint16_t f2u(float f) {
    __bf16 b = (__bf16)f;                       // native RNE cvt on gfx950
    return __builtin_bit_cast(uint16_t, b);
}
__device__ __forceinline__ ushort4 pack4(float a, float b, float c, float d) {
    ushort4 o;
    o.x = f2u(a); o.y = f2u(b); o.z = f2u(c); o.w = f2u(d);
    return o;
}

// ws layout (uint16 elems)
static constexpr size_t WCSE   = 0;                    // bf16 [8192][512]
static constexpr size_t WTW1SE = 4194304;              // bf16 [512][256]
static constexpr size_t WTW1UE = WTW1SE + 131072;      // bf16 [512][128]
static constexpr size_t WTW2   = WTW1UE + 65536;       // bf16 [256][512]
static constexpr size_t WUW2   = WTW2 + 131072;        // bf16 [128][128]
static constexpr size_t WSW2   = WUW2 + 16384;         // bf16 [256][256]
static constexpr size_t WUW1B  = WSW2 + 65536;         // bf16 [128][32] 0-pad

// ---------------- k_conv: all weights fp32 -> bf16 (404 blocks) ------------
__global__ __launch_bounds__(256) void k_conv(
    const float* __restrict__ tw1, const float* __restrict__ tw2,
    const float* __restrict__ uw2, const float* __restrict__ sw2,
    const float* __restrict__ uw1, uint16_t* __restrict__ ws)
{
    int i4 = blockIdx.x * 256 + threadIdx.x;
    if (i4 >= 102400) {                          // uw1b: zero-padded K=32
        int q = i4 - 102400;                     // [0,1024)
        int n = q >> 3, k0 = (q & 7) * 4;
        ushort4 o = {0, 0, 0, 0};
        if (k0 < 8) {
            float4 v = *reinterpret_cast<const float4*>(uw1 + n * 8 + k0);
            o.x = f2u(v.x); o.y = f2u(v.y); o.z = f2u(v.z); o.w = f2u(v.w);
        }
        *reinterpret_cast<ushort4*>(ws + WUW1B + n * 32 + k0) = o;
        return;
    }
    const float* src; size_t dst;
    if (i4 < 32768) {                            // tw1 se-part (k<256)
        int g = i4 * 4, n = g >> 8, k = g & 255;
        src = tw1 + (size_t)n * 384 + k;
        dst = WTW1SE + (size_t)g;
    } else if (i4 < 49152) {                     // tw1 ue-part (k>=256)
        int q = i4 - 32768, n = q >> 5, w = q & 31;
        src = tw1 + (size_t)n * 384 + 256 + w * 4;
        dst = WTW1UE + (size_t)n * 128 + w * 4;
    } else if (i4 < 81920) {
        int q = (i4 - 49152) * 4;
        src = tw2 + q; dst = WTW2 + q;
    } else if (i4 < 86016) {
        int q = (i4 - 81920) * 4;
        src = uw2 + q; dst = WUW2 + q;
    } else {
        int q = (i4 - 86016) * 4;
        src = sw2 + q; dst = WSW2 + q;
    }
    float4 v = *reinterpret_cast<const float4*>(src);
    ushort4 o;
    o.x = f2u(v.x); o.y = f2u(v.y); o.z = f2u(v.z); o.w = f2u(v.w);
    *reinterpret_cast<ushort4*>(ws + dst) = o;
}

// ---------------- k_cse: se + cse, 16 elems/block, 512 thr (512 blocks) ----
__global__ __launch_bounds__(512) void k_cse(
    const float* __restrict__ obs,
    const float* __restrict__ sw1, const float* __restrict__ sb1,
    const float* __restrict__ sb2, const float* __restrict__ tb1,
    uint16_t* __restrict__ ws)
{
    __shared__ float xs[16][24];
    __shared__ uint16_t h1s[16 * 264];
    __shared__ uint16_t seL[16 * 264];
    const int t = threadIdx.x;
    const int b0 = blockIdx.x * 16;
    const int wv = t >> 6, lane = t & 63, quad = lane >> 4, l16 = lane & 15;
    const uint16_t* sw2b   = ws + WSW2;
    const uint16_t* tw1seb = ws + WTW1SE;

    if (t < 352) {
        int e = t / 22, c = t - e * 22;
        xs[e][c] = obs[(size_t)(b0 + e) * 150 + c];
    }
    __syncthreads();
    // issue-early: se-L2 phase's first B pair (in flight through L1)
    const uint16_t* bb_se = sw2b + (size_t)(wv * 32 + l16) * 256 + quad * 8;
    bf16x8 seb0 = *reinterpret_cast<const bf16x8*>(bb_se);
    bf16x8 seb1 = *reinterpret_cast<const bf16x8*>(bb_se + 4096);
    {   // shared L1 (VALU): neuron t&255, 8 elems each
        const int n = t & 255;
        float w[22];
        #pragma unroll
        for (int k = 0; k < 22; ++k) w[k] = sw1[n * 22 + k];
        const float bias = sb1[n];
        #pragma unroll
        for (int ii = 0; ii < 8; ++ii) {
            int e = (t >> 8) * 8 + ii;
            float a = bias;
            #pragma unroll
            for (int k = 0; k < 22; ++k) a += w[k] * xs[e][k];
            h1s[e * 264 + n] = f2u(fmaxf(a, 0.f));
        }
    }
    __syncthreads();
    // issue-early: cse phase's first 4 B fragments (in flight through se-L2)
    const uint16_t* bb_c = tw1seb + (size_t)(wv * 64 + l16) * 256 + quad * 8;
    bf16x8 cseb[4];
    #pragma unroll
    for (int nt = 0; nt < 4; ++nt)
        cseb[nt] = *reinterpret_cast<const bf16x8*>(bb_c + nt * 4096);
    {   // shared L2 (MFMA): M=16, wave N=32, K=256, depth-2 B -> seL
        f32x4 acc[2];
        #pragma unroll
        for (int nt = 0; nt < 2; ++nt) {
            float bv = sb2[wv * 32 + nt * 16 + l16];
            acc[nt] = {bv, bv, bv, bv};
        }
        bf16x8 sA[2], sB[2];
        sA[0] = seb0; sB[0] = seb1;
        sA[1] = *reinterpret_cast<const bf16x8*>(bb_se + 32);
        sB[1] = *reinterpret_cast<const bf16x8*>(bb_se + 4096 + 32);
        #pragma unroll
        for (int kk = 0; kk < 8; ++kk) {
            bf16x8 c0 = sA[kk & 1], c1 = sB[kk & 1];
            if (kk < 6) {
                sA[kk & 1] = *reinterpret_cast<const bf16x8*>(
                    bb_se + (kk + 2) * 32);
                sB[kk & 1] = *reinterpret_cast<const bf16x8*>(
                    bb_se + 4096 + (kk + 2) * 32);
            }
            bf16x8 af = *reinterpret_cast<const bf16x8*>(
                &h1s[l16 * 264 + kk * 32 + quad * 8]);
            acc[0] = __builtin_amdgcn_mfma_f32_16x16x32_bf16(af, c0, acc[0], 0, 0, 0);
            acc[1] = __builtin_amdgcn_mfma_f32_16x16x32_bf16(af, c1, acc[1], 0, 0, 0);
        }
        #pragma unroll
        for (int nt = 0; nt < 2; ++nt)
            #pragma unroll
            for (int r = 0; r < 4; ++r)
                seL[(quad * 4 + r) * 264 + wv * 32 + nt * 16 + l16] =
                    f2u(fmaxf(acc[nt][r], 0.f));
    }
    __syncthreads();
    {   // cse (MFMA): M=16, wave N=64, K=256, depth-2 B, no relu -> ws
        f32x4 acc[4];
        #pragma unroll
        for (int nt = 0; nt < 4; ++nt) {
            float bv = tb1[wv * 64 + nt * 16 + l16];
            acc[nt] = {bv, bv, bv, bv};
        }
        bf16x8 q0[4], q1[4];
        #pragma unroll
        for (int nt = 0; nt < 4; ++nt) q0[nt] = cseb[nt];
        #pragma unroll
        for (int nt = 0; nt < 4; ++nt)
            q1[nt] = *reinterpret_cast<const bf16x8*>(bb_c + nt * 4096 + 32);
        #pragma unroll
        for (int kk = 0; kk < 8; ++kk) {
            bf16x8 cur[4];
            #pragma unroll
            for (int nt = 0; nt < 4; ++nt)
                cur[nt] = (kk & 1) ? q1[nt] : q0[nt];
            if (kk < 6) {
                #pragma unroll
                for (int nt = 0; nt < 4; ++nt) {
                    bf16x8 v = *reinterpret_cast<const bf16x8*>(
                        bb_c + nt * 4096 + (kk + 2) * 32);
                    if (kk & 1) q1[nt] = v; else q0[nt] = v;
                }
            }
            bf16x8 af = *reinterpret_cast<const bf16x8*>(
                &seL[l16 * 264 + kk * 32 + quad * 8]);
            #pragma unroll
            for (int nt = 0; nt < 4; ++nt)
                acc[nt] = __builtin_amdgcn_mfma_f32_16x16x32_bf16(
                    af, cur[nt], acc[nt], 0, 0, 0);
        }
        #pragma unroll
        for (int nt = 0; nt < 4; ++nt)
            #pragma unroll
            for (int r = 0; r < 4; ++r)
                ws[WCSE + (size_t)(b0 + quad * 4 + r) * 512 +
                   wv * 64 + nt * 16 + l16] = f2u(acc[nt][r]);
    }
}

// ---- k_main (swapped MFMAs, in-reg heads, deferred cse, depth-2 pipe) -----
// LDS (bytes): uqb bf16[64][40] 0..5120 | noop f32[64] @5120 | cse bf16[4][512]
// @5376 | h1u bf16[64][136] @9472 | uet @26880 | h1t bf16[64][264] @44288
// (hred f32[1024] overlays h1t after trunk) -> 78080 B, 2 blocks/CU.
static constexpr int UQB_OFF  = 0;
static constexpr int NOOP_OFF = 5120;
static constexpr int CSE_OFF  = 5376;
static constexpr int H1U_OFF  = 9472;
static constexpr int UET_OFF  = 26880;
static constexpr int H1T_OFF  = 44288;
static constexpr int SMEM_SZ  = 78080;

__global__ __launch_bounds__(512, 4) void k_main(
    const float* __restrict__ obs,
    const float* __restrict__ ub1,
    const float* __restrict__ ub2, const float* __restrict__ emb,
    const float* __restrict__ tb2,
    const float* __restrict__ vw,  const float* __restrict__ vb,
    const float* __restrict__ dw,  const float* __restrict__ db,
    const uint16_t* __restrict__ wsb,
    float* __restrict__ out)
{
    __shared__ __align__(16) char smem[SMEM_SZ];
    uint16_t* uqb   = (uint16_t*)(smem + UQB_OFF);
    float*    noopf = (float*)(smem + NOOP_OFF);
    uint16_t* cseL  = (uint16_t*)(smem + CSE_OFF);
    uint16_t* h1u   = (uint16_t*)(smem + H1U_OFF);
    uint16_t* uet   = (uint16_t*)(smem + UET_OFF);
    uint16_t* h1t   = (uint16_t*)(smem + H1T_OFF);
    float*    hred  = (float*)(smem + H1T_OFF);

    const int t    = threadIdx.x;
    const int wv   = t >> 6;
    const int lane = t & 63;
    const int quad = lane >> 4;
    const int l16  = lane & 15;
    const int b0   = blockIdx.x * 4;

    const uint16_t* csep  = wsb + WCSE;
    const uint16_t* tw1ue = wsb + WTW1UE;
    const uint16_t* tw2b  = wsb + WTW2;
    const uint16_t* uw2b  = wsb + WUW2;
    const uint16_t* uw1b  = wsb + WUW1B;

    // ---- stage 1: uqb bf16 [64][40] (K=32 zero-padded), noop; cse -> regs --
    uint32_t cse_r0, cse_r1;
    bf16x8 wf2;                                  // stage2 W (issue-early)
    float4 bv1_4;                                // stage2 bias (issue-early)
    {
        int r = t >> 3, q = t & 7;               // row 0..63, k-quad 0..7
        int e = r >> 4, o = r & 15;
        ushort4 ov = {0, 0, 0, 0};
        if (q < 2) {                             // cols 0..7 real (8B-aligned)
            const float2* sp = reinterpret_cast<const float2*>(
                &obs[(size_t)(b0 + e) * 150 + 22 + o * 8 + q * 4]);
            float2 a = sp[0], b = sp[1];
            ov.x = f2u(a.x); ov.y = f2u(a.y); ov.z = f2u(b.x); ov.w = f2u(b.y);
        }
        *reinterpret_cast<ushort4*>(&uqb[r * 40 + q * 4]) = ov;
        const uint32_t* cp = (const uint32_t*)(csep + (size_t)b0 * 512);
        cse_r0 = cp[t];
        cse_r1 = cp[t + 512];
        wf2 = *reinterpret_cast<const bf16x8*>(
            &uw1b[(wv * 16 + l16) * 32 + quad * 8]);
        bv1_4 = *reinterpret_cast<const float4*>(&ub1[wv * 16 + quad * 4]);
        if (t < 64) {
            int ee = t >> 4, oo = t & 15;
            noopf[t] = (obs[(size_t)(b0 + ee) * 150 + 22 + oo * 8] == 1.0f) ? 1.0f : 0.0f;
        }
    }
    __syncthreads();

    // ---- stage 2: unique L1, swapped mfma(W,X) -> b64 stores ----
    bf16x8 wf3;                                  // stage3 kk=0 W (issue-early)
    float4 bv2_4, ev_4;                          // stage3 bias/emb (issue-early)
    {
        f32x4 acc[4];
        #pragma unroll
        for (int mt = 0; mt < 4; ++mt) acc[mt] = {bv1_4.x, bv1_4.y, bv1_4.z, bv1_4.w};
        #pragma unroll
        for (int mt = 0; mt < 4; ++mt) {
            bf16x8 xf = *reinterpret_cast<const bf16x8*>(
                &uqb[(mt * 16 + l16) * 40 + quad * 8]);
            acc[mt] = __builtin_amdgcn_mfma_f32_16x16x32_bf16(wf2, xf, acc[mt], 0, 0, 0);
        }
        wf3 = *reinterpret_cast<const bf16x8*>(
            &uw2b[(size_t)(wv * 16 + l16) * 128 + quad * 8]);
        bv2_4 = *reinterpret_cast<const float4*>(&ub2[wv * 16 + quad * 4]);
        ev_4  = *reinterpret_cast<const float4*>(&emb[wv * 16 + quad * 4]);
        #pragma unroll
        for (int mt = 0; mt < 4; ++mt) {
            ushort4 o = pack4(fmaxf(acc[mt][0], 0.f), fmaxf(acc[mt][1], 0.f),
                              fmaxf(acc[mt][2], 0.f), fmaxf(acc[mt][3], 0.f));
            *reinterpret_cast<ushort4*>(
                &h1u[(mt * 16 + l16) * 136 + wv * 16 + quad * 4]) = o;
        }
    }
    __syncthreads();

    // ---- stage 3: unique L2, swapped, K=128, depth-2 W chain -> uet ----
    float4 tb2_4[2];                             // trunk bias (issue-early)
    {
        f32x4 acc[4];
        #pragma unroll
        for (int mt = 0; mt < 4; ++mt) acc[mt] = {bv2_4.x, bv2_4.y, bv2_4.z, bv2_4.w};
        bf16x8 w0 = wf3;
        bf16x8 w1 = *reinterpret_cast<const bf16x8*>(
            &uw2b[(size_t)(wv * 16 + l16) * 128 + 32 + quad * 8]);
        #pragma unroll
        for (int kk = 0; kk < 4; ++kk) {
            bf16x8 cur = (kk & 1) ? w1 : w0;
            if (kk < 2) {
                bf16x8 v = *reinterpret_cast<const bf16x8*>(
                    &uw2b[(size_t)(wv * 16 + l16) * 128 + (kk + 2) * 32 + quad * 8]);
                if (kk & 1) w1 = v; else w0 = v;
            }
            #pragma unroll
            for (int mt = 0; mt < 4; ++mt) {
                bf16x8 xf = *reinterpret_cast<const bf16x8*>(
                    &h1u[(mt * 16 + l16) * 136 + kk * 32 + quad * 8]);
                acc[mt] = __builtin_amdgcn_mfma_f32_16x16x32_bf16(cur, xf, acc[mt], 0, 0, 0);
            }
        }
        #pragma unroll
        for (int nt = 0; nt < 2; ++nt)
            tb2_4[nt] = *reinterpret_cast<const float4*>(
                &tb2[wv * 32 + nt * 16 + quad * 4]);
        #pragma unroll
        for (int mt = 0; mt < 4; ++mt) {
            bool noop = (noopf[mt * 16 + l16] != 0.0f);
            ushort4 o = pack4(noop ? ev_4.x : fmaxf(acc[mt][0], 0.f),
                              noop ? ev_4.y : fmaxf(acc[mt][1], 0.f),
                              noop ? ev_4.z : fmaxf(acc[mt][2], 0.f),
                              noop ? ev_4.w : fmaxf(acc[mt][3], 0.f));
            *reinterpret_cast<ushort4*>(
                &uet[(mt * 16 + l16) * 136 + wv * 16 + quad * 4]) = o;
        }
        // deferred cse LDS write (loads issued in stage 1, latency hidden)
        ((uint32_t*)cseL)[t] = cse_r0;
        ((uint32_t*)cseL)[t + 512] = cse_r1;
    }
    __syncthreads();

    // ---- trunk: 2 N-chunks of 256; depth-2 pipes on L1 and L2 ----
    f32x4 acc2[4][2];
    #pragma unroll
    for (int nt = 0; nt < 2; ++nt) {
        #pragma unroll
        for (int mt = 0; mt < 4; ++mt)
            acc2[mt][nt] = {tb2_4[nt].x, tb2_4[nt].y, tb2_4[nt].z, tb2_4[nt].w};
    }

    const uint16_t* tw1ue_base = tw1ue + (size_t)(wv * 32 + l16) * 128 + quad * 8;
    bf16x8 bc[2];                                // L1 slot-0 (kk even)
    bc[0] = *reinterpret_cast<const bf16x8*>(tw1ue_base);
    bc[1] = *reinterpret_cast<const bf16x8*>(tw1ue_base + 2048);

    #pragma unroll
    for (int nc = 0; nc < 2; ++nc) {
        const uint16_t* bb = tw1ue_base + (size_t)nc * 32768;
        const uint16_t* cb = tw2b + (size_t)(wv * 32 + l16) * 512 + nc * 256
                             + quad * 8;
        // issue-early: this nc's L2-phase k2=0 B (in flight through L1 phase)
        bf16x8 cc[2];
        cc[0] = *reinterpret_cast<const bf16x8*>(cb);
        cc[1] = *reinterpret_cast<const bf16x8*>(cb + 8192);
        {
            // L1 slot-1 (kk odd) preload
            bf16x8 b1s[2];
            b1s[0] = *reinterpret_cast<const bf16x8*>(bb + 32);
            b1s[1] = *reinterpret_cast<const bf16x8*>(bb + 2048 + 32);
            f32x4 acc1[4][2];
            #pragma unroll
            for (int nt = 0; nt < 2; ++nt) {
                int n0 = nc * 256 + wv * 32 + nt * 16 + quad * 4;
                #pragma unroll
                for (int mt = 0; mt < 4; ++mt) {
                    ushort4 cv = *reinterpret_cast<const ushort4*>(
                        &cseL[mt * 512 + n0]);
                    acc1[mt][nt] = {u2f(cv.x), u2f(cv.y), u2f(cv.z), u2f(cv.w)};
                }
            }
            #pragma unroll
            for (int kk = 0; kk < 4; ++kk) {
                bf16x8 cur0 = (kk & 1) ? b1s[0] : bc[0];
                bf16x8 cur1 = (kk & 1) ? b1s[1] : bc[1];
                if (kk < 2) {
                    bf16x8 v0 = *reinterpret_cast<const bf16x8*>(bb + (kk + 2) * 32);
                    bf16x8 v1 = *reinterpret_cast<const bf16x8*>(bb + 2048 + (kk + 2) * 32);
                    if (kk & 1) { b1s[0] = v0; b1s[1] = v1; }
                    else        { bc[0] = v0;  bc[1] = v1; }
                }
                bf16x8 af[4];
                #pragma unroll
                for (int mt = 0; mt < 4; ++mt)
                    af[mt] = *reinterpret_cast<const bf16x8*>(
                        &uet[(mt * 16 + l16) * 136 + kk * 32 + quad * 8]);
                #pragma unroll
                for (int mt = 0; mt < 4; ++mt) {
                    acc1[mt][0] = __builtin_amdgcn_mfma_f32_16x16x32_bf16(
                        cur0, af[mt], acc1[mt][0], 0, 0, 0);
                    acc1[mt][1] = __builtin_amdgcn_mfma_f32_16x16x32_bf16(
                        cur1, af[mt], acc1[mt][1], 0, 0, 0);
                }
            }
            if (nc == 0) {   // issue-early: nc=1 L1 kk=0 (in flight through L2)
                bc[0] = *reinterpret_cast<const bf16x8*>(tw1ue_base + 32768);
                bc[1] = *reinterpret_cast<const bf16x8*>(tw1ue_base + 32768 + 2048);
            }
            #pragma unroll
            for (int mt = 0; mt < 4; ++mt)
                #pragma unroll
                for (int nt = 0; nt < 2; ++nt) {
                    ushort4 o = pack4(fmaxf(acc1[mt][nt][0], 0.f),
                                      fmaxf(acc1[mt][nt][1], 0.f),
                                      fmaxf(acc1[mt][nt][2], 0.f),
                                      fmaxf(acc1[mt][nt][3], 0.f));
                    *reinterpret_cast<ushort4*>(
                        &h1t[(mt * 16 + l16) * 264 + wv * 32 + nt * 16 + quad * 4]) = o;
                }
        }
        __syncthreads();
        {
            // L2 slot-1 (k2 odd) preload
            bf16x8 c1s[2];
            c1s[0] = *reinterpret_cast<const bf16x8*>(cb + 32);
            c1s[1] = *reinterpret_cast<const bf16x8*>(cb + 8192 + 32);
            #pragma unroll
            for (int k2 = 0; k2 < 8; ++k2) {
                bf16x8 cur0 = (k2 & 1) ? c1s[0] : cc[0];
                bf16x8 cur1 = (k2 & 1) ? c1s[1] : cc[1];
                if (k2 < 6) {
                    bf16x8 v0 = *reinterpret_cast<const bf16x8*>(cb + (k2 + 2) * 32);
                    bf16x8 v1 = *reinterpret_cast<const bf16x8*>(cb + 8192 + (k2 + 2) * 32);
                    if (k2 & 1) { c1s[0] = v0; c1s[1] = v1; }
                    else        { cc[0] = v0;  cc[1] = v1; }
                }
                bf16x8 af[4];
                #pragma unroll
                for (int mt = 0; mt < 4; ++mt)
                    af[mt] = *reinterpret_cast<const bf16x8*>(
                        &h1t[(mt * 16 + l16) * 264 + k2 * 32 + quad * 8]);
                #pragma unroll
                for (int mt = 0; mt < 4; ++mt) {
                    acc2[mt][0] = __builtin_amdgcn_mfma_f32_16x16x32_bf16(
                        cur0, af[mt], acc2[mt][0], 0, 0, 0);
                    acc2[mt][1] = __builtin_amdgcn_mfma_f32_16x16x32_bf16(
                        cur1, af[mt], acc2[mt][1], 0, 0, 0);
                }
            }
        }
        if (nc == 0) __syncthreads();
    }
    __syncthreads();                             // last h1t read done

    // ---- heads: in-register from acc2 (fp32 t, no bf16 round) ----
    {
        float svr[4] = {0.f, 0.f, 0.f, 0.f};
        float sdr[4] = {0.f, 0.f, 0.f, 0.f};
        #pragma unroll
        for (int nt = 0; nt < 2; ++nt) {
            float4 vw4 = *reinterpret_cast<const float4*>(
                &vw[wv * 32 + nt * 16 + quad * 4]);
            float4 dw4 = *reinterpret_cast<const float4*>(
                &dw[wv * 32 + nt * 16 + quad * 4]);
            #pragma unroll
            for (int mt = 0; mt < 4; ++mt) {
                float t0 = fmaxf(acc2[mt][nt][0], 0.f);
                float t1 = fmaxf(acc2[mt][nt][1], 0.f);
                float t2 = fmaxf(acc2[mt][nt][2], 0.f);
                float t3 = fmaxf(acc2[mt][nt][3], 0.f);
                svr[mt] += t0 * vw4.x + t1 * vw4.y + t2 * vw4.z + t3 * vw4.w;
                sdr[mt] += t0 * dw4.x + t1 * dw4.y + t2 * dw4.z + t3 * dw4.w;
            }
        }
        #pragma unroll
        for (int mt = 0; mt < 4; ++mt) {         // reduce over quads
            svr[mt] += __shfl_xor(svr[mt], 16);
            svr[mt] += __shfl_xor(svr[mt], 32);
            sdr[mt] += __shfl_xor(sdr[mt], 16);
            sdr[mt] += __shfl_xor(sdr[mt], 32);
        }
        if (quad == 0) {                         // stage per-wave partials
            #pragma unroll
            for (int mt = 0; mt < 4; ++mt) {
                int row = mt * 16 + l16;
                hred[(row * 2 + 0) * 8 + wv] = svr[mt];
                hred[(row * 2 + 1) * 8 + wv] = sdr[mt];
            }
        }
    }
    __syncthreads();
    if (t < 128) {                               // final reduce over 8 waves
        const float* p = &hred[t * 8];
        float s = p[0] + p[1] + p[2] + p[3] + p[4] + p[5] + p[6] + p[7];
        int row = t >> 1;
        int g = blockIdx.x * 64 + row;
        if ((t & 1) == 0) {
            out[g] = s + vb[0];
        } else {
            float z = s + db[0];
            float sig = 1.f / (1.f + __expf(-z));
            out[B_ * 16 + g] = sig * 0.4f + 0.1f;
        }
    }
}

extern "C" void kernel_launch(void* const* d_in, const int* in_sizes, int n_in,
                              void* d_out, int out_size, void* d_ws, size_t ws_size,
                              hipStream_t stream) {
    const float* obs = (const float*)d_in[0];
    const float* sw1 = (const float*)d_in[1];
    const float* sb1 = (const float*)d_in[2];
    const float* sw2 = (const float*)d_in[3];
    const float* sb2 = (const float*)d_in[4];
    const float* uw1 = (const float*)d_in[5];
    const float* ub1 = (const float*)d_in[6];
    const float* uw2 = (const float*)d_in[7];
    const float* ub2 = (const float*)d_in[8];
    const float* emb = (const float*)d_in[9];
    const float* tw1 = (const float*)d_in[10];
    const float* tb1 = (const float*)d_in[11];
    const float* tw2 = (const float*)d_in[12];
    const float* tb2 = (const float*)d_in[13];
    const float* vw  = (const float*)d_in[14];
    const float* vb  = (const float*)d_in[15];
    const float* dw  = (const float*)d_in[16];
    const float* db  = (const float*)d_in[17];

    uint16_t* wsb = (uint16_t*)d_ws;

    k_conv<<<404, 256, 0, stream>>>(tw1, tw2, uw2, sw2, uw1, wsb);
    k_cse<<<512, 512, 0, stream>>>(obs, sw1, sb1, sb2, tb1, wsb);
    k_main<<<B_ / 4, 512, 0, stream>>>(obs, ub1, ub2, emb, tb2,
                                       vw, vb, dw, db, wsb, (float*)d_out);
}

// Round 14
// 221.654 us; speedup vs baseline: 1.7913x; 1.0115x over previous
//
#include <hip/hip_runtime.h>
#include <stdint.h>

// GaitnetActor B=8192, OPT=16. Round 31: FINAL — exact R29 restore (best
// measured: k_main 118.0us, total 222-225 band). R30's depth-2 pipelining
// regressed (+2us: slot-select v_cndmask chains on the critical path;
// compiler's depth-1 schedule already adequate). Configuration: 3 kernels
// (k_conv 404 / k_cse M=16x512 / k_main M=64x2048, 2 blocks/CU) with
// swapped-operand MFMAs (packed b64 LDS stores), in-register heads,
// deferred cse LDS write, issue-early B-fragment + bias hoists across every
// barrier, native RNE bf16 cvt. Plateau evidence: MfmaUtil 19.5 (compute
// floor ~23us), HBM 1% (L2 weight stream ~25us), latency-bound across 9
// barrier phases at 16 waves/CU; 3rd block reg-capped (R19/R21 spills),
// M-rebalance traffic-capped (R18/R21/R28), sched hints null (R27/R30).
// out[0:131072]=logits fp32, [131072:262144]=duration fp32.

static constexpr int B_ = 8192;

typedef __attribute__((ext_vector_type(8))) short bf16x8;
typedef __attribute__((ext_vector_type(4))) float f32x4;

__device__ __forceinline__ float u2f(uint16_t u) {
    union { uint32_t i; float f; } c; c.i = (uint32_t)u << 16; return c.f;
}
__device__ __forceinline__ uint16_t f2u(float f) {
    __bf16 b = (__bf16)f;                       // native RNE cvt on gfx950
    return __builtin_bit_cast(uint16_t, b);
}
__device__ __forceinline__ ushort4 pack4(float a, float b, float c, float d) {
    ushort4 o;
    o.x = f2u(a); o.y = f2u(b); o.z = f2u(c); o.w = f2u(d);
    return o;
}

// ws layout (uint16 elems)
static constexpr size_t WCSE   = 0;                    // bf16 [8192][512]
static constexpr size_t WTW1SE = 4194304;              // bf16 [512][256]
static constexpr size_t WTW1UE = WTW1SE + 131072;      // bf16 [512][128]
static constexpr size_t WTW2   = WTW1UE + 65536;       // bf16 [256][512]
static constexpr size_t WUW2   = WTW2 + 131072;        // bf16 [128][128]
static constexpr size_t WSW2   = WUW2 + 16384;         // bf16 [256][256]
static constexpr size_t WUW1B  = WSW2 + 65536;         // bf16 [128][32] 0-pad

// ---------------- k_conv: all weights fp32 -> bf16 (404 blocks) ------------
__global__ __launch_bounds__(256) void k_conv(
    const float* __restrict__ tw1, const float* __restrict__ tw2,
    const float* __restrict__ uw2, const float* __restrict__ sw2,
    const float* __restrict__ uw1, uint16_t* __restrict__ ws)
{
    int i4 = blockIdx.x * 256 + threadIdx.x;
    if (i4 >= 102400) {                          // uw1b: zero-padded K=32
        int q = i4 - 102400;                     // [0,1024)
        int n = q >> 3, k0 = (q & 7) * 4;
        ushort4 o = {0, 0, 0, 0};
        if (k0 < 8) {
            float4 v = *reinterpret_cast<const float4*>(uw1 + n * 8 + k0);
            o.x = f2u(v.x); o.y = f2u(v.y); o.z = f2u(v.z); o.w = f2u(v.w);
        }
        *reinterpret_cast<ushort4*>(ws + WUW1B + n * 32 + k0) = o;
        return;
    }
    const float* src; size_t dst;
    if (i4 < 32768) {                            // tw1 se-part (k<256)
        int g = i4 * 4, n = g >> 8, k = g & 255;
        src = tw1 + (size_t)n * 384 + k;
        dst = WTW1SE + (size_t)g;
    } else if (i4 < 49152) {                     // tw1 ue-part (k>=256)
        int q = i4 - 32768, n = q >> 5, w = q & 31;
        src = tw1 + (size_t)n * 384 + 256 + w * 4;
        dst = WTW1UE + (size_t)n * 128 + w * 4;
    } else if (i4 < 81920) {
        int q = (i4 - 49152) * 4;
        src = tw2 + q; dst = WTW2 + q;
    } else if (i4 < 86016) {
        int q = (i4 - 81920) * 4;
        src = uw2 + q; dst = WUW2 + q;
    } else {
        int q = (i4 - 86016) * 4;
        src = sw2 + q; dst = WSW2 + q;
    }
    float4 v = *reinterpret_cast<const float4*>(src);
    ushort4 o;
    o.x = f2u(v.x); o.y = f2u(v.y); o.z = f2u(v.z); o.w = f2u(v.w);
    *reinterpret_cast<ushort4*>(ws + dst) = o;
}

// ---------------- k_cse: se + cse, 16 elems/block, 512 thr (512 blocks) ----
__global__ __launch_bounds__(512) void k_cse(
    const float* __restrict__ obs,
    const float* __restrict__ sw1, const float* __restrict__ sb1,
    const float* __restrict__ sb2, const float* __restrict__ tb1,
    uint16_t* __restrict__ ws)
{
    __shared__ float xs[16][24];
    __shared__ uint16_t h1s[16 * 264];
    __shared__ uint16_t seL[16 * 264];
    const int t = threadIdx.x;
    const int b0 = blockIdx.x * 16;
    const int wv = t >> 6, lane = t & 63, quad = lane >> 4, l16 = lane & 15;
    const uint16_t* sw2b   = ws + WSW2;
    const uint16_t* tw1seb = ws + WTW1SE;

    if (t < 352) {
        int e = t / 22, c = t - e * 22;
        xs[e][c] = obs[(size_t)(b0 + e) * 150 + c];
    }
    __syncthreads();
    // issue-early: shared-L2 phase's first B pair (in flight through L1)
    const uint16_t* bb_se = sw2b + (size_t)(wv * 32 + l16) * 256 + quad * 8;
    bf16x8 seb0 = *reinterpret_cast<const bf16x8*>(bb_se);
    bf16x8 seb1 = *reinterpret_cast<const bf16x8*>(bb_se + 4096);
    {   // shared L1 (VALU): neuron t&255, 8 elems each
        const int n = t & 255;
        float w[22];
        #pragma unroll
        for (int k = 0; k < 22; ++k) w[k] = sw1[n * 22 + k];
        const float bias = sb1[n];
        #pragma unroll
        for (int ii = 0; ii < 8; ++ii) {
            int e = (t >> 8) * 8 + ii;
            float a = bias;
            #pragma unroll
            for (int k = 0; k < 22; ++k) a += w[k] * xs[e][k];
            h1s[e * 264 + n] = f2u(fmaxf(a, 0.f));
        }
    }
    __syncthreads();
    // issue-early: cse phase's first 4 B fragments (in flight through se-L2)
    const uint16_t* bb_c = tw1seb + (size_t)(wv * 64 + l16) * 256 + quad * 8;
    bf16x8 cseb[4];
    #pragma unroll
    for (int nt = 0; nt < 4; ++nt)
        cseb[nt] = *reinterpret_cast<const bf16x8*>(bb_c + nt * 4096);
    {   // shared L2 (MFMA): M=16, wave N=32, K=256 -> seL
        f32x4 acc[2];
        #pragma unroll
        for (int nt = 0; nt < 2; ++nt) {
            float bv = sb2[wv * 32 + nt * 16 + l16];
            acc[nt] = {bv, bv, bv, bv};
        }
        bf16x8 bc[2], bn[2];
        bc[0] = seb0; bc[1] = seb1;
        #pragma unroll
        for (int kk = 0; kk < 8; ++kk) {
            if (kk < 7) {
                bn[0] = *reinterpret_cast<const bf16x8*>(bb_se + (kk + 1) * 32);
                bn[1] = *reinterpret_cast<const bf16x8*>(bb_se + 4096 + (kk + 1) * 32);
            }
            bf16x8 af = *reinterpret_cast<const bf16x8*>(
                &h1s[l16 * 264 + kk * 32 + quad * 8]);
            #pragma unroll
            for (int nt = 0; nt < 2; ++nt)
                acc[nt] = __builtin_amdgcn_mfma_f32_16x16x32_bf16(
                    af, bc[nt], acc[nt], 0, 0, 0);
            bc[0] = bn[0]; bc[1] = bn[1];
        }
        #pragma unroll
        for (int nt = 0; nt < 2; ++nt)
            #pragma unroll
            for (int r = 0; r < 4; ++r)
                seL[(quad * 4 + r) * 264 + wv * 32 + nt * 16 + l16] =
                    f2u(fmaxf(acc[nt][r], 0.f));
    }
    __syncthreads();
    {   // cse (MFMA): M=16, wave N=64, K=256, no relu -> ws
        f32x4 acc[4];
        #pragma unroll
        for (int nt = 0; nt < 4; ++nt) {
            float bv = tb1[wv * 64 + nt * 16 + l16];
            acc[nt] = {bv, bv, bv, bv};
        }
        bf16x8 bc[4], bn[4];
        #pragma unroll
        for (int nt = 0; nt < 4; ++nt) bc[nt] = cseb[nt];
        #pragma unroll
        for (int kk = 0; kk < 8; ++kk) {
            if (kk < 7) {
                #pragma unroll
                for (int nt = 0; nt < 4; ++nt)
                    bn[nt] = *reinterpret_cast<const bf16x8*>(
                        bb_c + nt * 4096 + (kk + 1) * 32);
            }
            bf16x8 af = *reinterpret_cast<const bf16x8*>(
                &seL[l16 * 264 + kk * 32 + quad * 8]);
            #pragma unroll
            for (int nt = 0; nt < 4; ++nt)
                acc[nt] = __builtin_amdgcn_mfma_f32_16x16x32_bf16(
                    af, bc[nt], acc[nt], 0, 0, 0);
            #pragma unroll
            for (int nt = 0; nt < 4; ++nt) bc[nt] = bn[nt];
        }
        #pragma unroll
        for (int nt = 0; nt < 4; ++nt)
            #pragma unroll
            for (int r = 0; r < 4; ++r)
                ws[WCSE + (size_t)(b0 + quad * 4 + r) * 512 +
                   wv * 64 + nt * 16 + l16] = f2u(acc[nt][r]);
    }
}

// ---- k_main (swapped MFMAs, in-reg heads, deferred cse, issue-early) ------
// LDS (bytes): uqb bf16[64][40] 0..5120 | noop f32[64] @5120 | cse bf16[4][512]
// @5376 | h1u bf16[64][136] @9472 | uet @26880 | h1t bf16[64][264] @44288
// (hred f32[1024] overlays h1t after trunk) -> 78080 B, 2 blocks/CU.
static constexpr int UQB_OFF  = 0;
static constexpr int NOOP_OFF = 5120;
static constexpr int CSE_OFF  = 5376;
static constexpr int H1U_OFF  = 9472;
static constexpr int UET_OFF  = 26880;
static constexpr int H1T_OFF  = 44288;
static constexpr int SMEM_SZ  = 78080;

__global__ __launch_bounds__(512, 4) void k_main(
    const float* __restrict__ obs,
    const float* __restrict__ ub1,
    const float* __restrict__ ub2, const float* __restrict__ emb,
    const float* __restrict__ tb2,
    const float* __restrict__ vw,  const float* __restrict__ vb,
    const float* __restrict__ dw,  const float* __restrict__ db,
    const uint16_t* __restrict__ wsb,
    float* __restrict__ out)
{
    __shared__ __align__(16) char smem[SMEM_SZ];
    uint16_t* uqb   = (uint16_t*)(smem + UQB_OFF);
    float*    noopf = (float*)(smem + NOOP_OFF);
    uint16_t* cseL  = (uint16_t*)(smem + CSE_OFF);
    uint16_t* h1u   = (uint16_t*)(smem + H1U_OFF);
    uint16_t* uet   = (uint16_t*)(smem + UET_OFF);
    uint16_t* h1t   = (uint16_t*)(smem + H1T_OFF);
    float*    hred  = (float*)(smem + H1T_OFF);

    const int t    = threadIdx.x;
    const int wv   = t >> 6;
    const int lane = t & 63;
    const int quad = lane >> 4;
    const int l16  = lane & 15;
    const int b0   = blockIdx.x * 4;

    const uint16_t* csep  = wsb + WCSE;
    const uint16_t* tw1ue = wsb + WTW1UE;
    const uint16_t* tw2b  = wsb + WTW2;
    const uint16_t* uw2b  = wsb + WUW2;
    const uint16_t* uw1b  = wsb + WUW1B;

    // ---- stage 1: uqb bf16 [64][40] (K=32 zero-padded), noop; cse -> regs --
    uint32_t cse_r0, cse_r1;
    bf16x8 wf2;                                  // stage2 W (issue-early)
    float4 bv1_4;                                // stage2 bias (issue-early)
    {
        int r = t >> 3, q = t & 7;               // row 0..63, k-quad 0..7
        int e = r >> 4, o = r & 15;
        ushort4 ov = {0, 0, 0, 0};
        if (q < 2) {                             // cols 0..7 real (8B-aligned)
            const float2* sp = reinterpret_cast<const float2*>(
                &obs[(size_t)(b0 + e) * 150 + 22 + o * 8 + q * 4]);
            float2 a = sp[0], b = sp[1];
            ov.x = f2u(a.x); ov.y = f2u(a.y); ov.z = f2u(b.x); ov.w = f2u(b.y);
        }
        *reinterpret_cast<ushort4*>(&uqb[r * 40 + q * 4]) = ov;
        const uint32_t* cp = (const uint32_t*)(csep + (size_t)b0 * 512);
        cse_r0 = cp[t];
        cse_r1 = cp[t + 512];
        wf2 = *reinterpret_cast<const bf16x8*>(
            &uw1b[(wv * 16 + l16) * 32 + quad * 8]);
        bv1_4 = *reinterpret_cast<const float4*>(&ub1[wv * 16 + quad * 4]);
        if (t < 64) {
            int ee = t >> 4, oo = t & 15;
            noopf[t] = (obs[(size_t)(b0 + ee) * 150 + 22 + oo * 8] == 1.0f) ? 1.0f : 0.0f;
        }
    }
    __syncthreads();

    // ---- stage 2: unique L1, swapped mfma(W,X) -> b64 stores ----
    bf16x8 wf3;                                  // stage3 kk=0 W (issue-early)
    float4 bv2_4, ev_4;                          // stage3 bias/emb (issue-early)
    {
        f32x4 acc[4];
        #pragma unroll
        for (int mt = 0; mt < 4; ++mt) acc[mt] = {bv1_4.x, bv1_4.y, bv1_4.z, bv1_4.w};
        #pragma unroll
        for (int mt = 0; mt < 4; ++mt) {
            bf16x8 xf = *reinterpret_cast<const bf16x8*>(
                &uqb[(mt * 16 + l16) * 40 + quad * 8]);
            acc[mt] = __builtin_amdgcn_mfma_f32_16x16x32_bf16(wf2, xf, acc[mt], 0, 0, 0);
        }
        wf3 = *reinterpret_cast<const bf16x8*>(
            &uw2b[(size_t)(wv * 16 + l16) * 128 + quad * 8]);
        bv2_4 = *reinterpret_cast<const float4*>(&ub2[wv * 16 + quad * 4]);
        ev_4  = *reinterpret_cast<const float4*>(&emb[wv * 16 + quad * 4]);
        #pragma unroll
        for (int mt = 0; mt < 4; ++mt) {
            ushort4 o = pack4(fmaxf(acc[mt][0], 0.f), fmaxf(acc[mt][1], 0.f),
                              fmaxf(acc[mt][2], 0.f), fmaxf(acc[mt][3], 0.f));
            *reinterpret_cast<ushort4*>(
                &h1u[(mt * 16 + l16) * 136 + wv * 16 + quad * 4]) = o;
        }
    }
    __syncthreads();

    // ---- stage 3: unique L2, swapped, K=128 -> uet (b64 stores) ----
    float4 tb2_4[2];                             // trunk bias (issue-early)
    {
        f32x4 acc[4];
        #pragma unroll
        for (int mt = 0; mt < 4; ++mt) acc[mt] = {bv2_4.x, bv2_4.y, bv2_4.z, bv2_4.w};
        bf16x8 wfc = wf3, wfn;
        #pragma unroll
        for (int kk = 0; kk < 4; ++kk) {
            if (kk < 3)
                wfn = *reinterpret_cast<const bf16x8*>(
                    &uw2b[(size_t)(wv * 16 + l16) * 128 + (kk + 1) * 32 + quad * 8]);
            #pragma unroll
            for (int mt = 0; mt < 4; ++mt) {
                bf16x8 xf = *reinterpret_cast<const bf16x8*>(
                    &h1u[(mt * 16 + l16) * 136 + kk * 32 + quad * 8]);
                acc[mt] = __builtin_amdgcn_mfma_f32_16x16x32_bf16(wfc, xf, acc[mt], 0, 0, 0);
            }
            wfc = wfn;
        }
        #pragma unroll
        for (int nt = 0; nt < 2; ++nt)
            tb2_4[nt] = *reinterpret_cast<const float4*>(
                &tb2[wv * 32 + nt * 16 + quad * 4]);
        #pragma unroll
        for (int mt = 0; mt < 4; ++mt) {
            bool noop = (noopf[mt * 16 + l16] != 0.0f);
            ushort4 o = pack4(noop ? ev_4.x : fmaxf(acc[mt][0], 0.f),
                              noop ? ev_4.y : fmaxf(acc[mt][1], 0.f),
                              noop ? ev_4.z : fmaxf(acc[mt][2], 0.f),
                              noop ? ev_4.w : fmaxf(acc[mt][3], 0.f));
            *reinterpret_cast<ushort4*>(
                &uet[(mt * 16 + l16) * 136 + wv * 16 + quad * 4]) = o;
        }
        // deferred cse LDS write (loads issued in stage 1, latency hidden)
        ((uint32_t*)cseL)[t] = cse_r0;
        ((uint32_t*)cseL)[t + 512] = cse_r1;
    }
    __syncthreads();

    // ---- trunk: 2 N-chunks of 256; swapped L1 (acc init = cse) -> L2 ----
    f32x4 acc2[4][2];
    #pragma unroll
    for (int nt = 0; nt < 2; ++nt) {
        #pragma unroll
        for (int mt = 0; mt < 4; ++mt)
            acc2[mt][nt] = {tb2_4[nt].x, tb2_4[nt].y, tb2_4[nt].z, tb2_4[nt].w};
    }

    const uint16_t* tw1ue_base = tw1ue + (size_t)(wv * 32 + l16) * 128 + quad * 8;
    bf16x8 bc[2], bn[2];
    bc[0] = *reinterpret_cast<const bf16x8*>(tw1ue_base);
    bc[1] = *reinterpret_cast<const bf16x8*>(tw1ue_base + 2048);

    #pragma unroll
    for (int nc = 0; nc < 2; ++nc) {
        const uint16_t* bb = tw1ue_base + (size_t)nc * 32768;
        const uint16_t* cb = tw2b + (size_t)(wv * 32 + l16) * 512 + nc * 256
                             + quad * 8;
        // issue-early: this nc's L2-phase B (in flight through L1 phase)
        bf16x8 cc[2], cn[2];
        cc[0] = *reinterpret_cast<const bf16x8*>(cb);
        cc[1] = *reinterpret_cast<const bf16x8*>(cb + 8192);
        {
            f32x4 acc1[4][2];
            #pragma unroll
            for (int nt = 0; nt < 2; ++nt) {
                int n0 = nc * 256 + wv * 32 + nt * 16 + quad * 4;
                #pragma unroll
                for (int mt = 0; mt < 4; ++mt) {
                    ushort4 cv = *reinterpret_cast<const ushort4*>(
                        &cseL[mt * 512 + n0]);
                    acc1[mt][nt] = {u2f(cv.x), u2f(cv.y), u2f(cv.z), u2f(cv.w)};
                }
            }
            #pragma unroll
            for (int kk = 0; kk < 4; ++kk) {
                if (kk < 3) {
                    bn[0] = *reinterpret_cast<const bf16x8*>(bb + (kk + 1) * 32);
                    bn[1] = *reinterpret_cast<const bf16x8*>(bb + 2048 + (kk + 1) * 32);
                }
                bf16x8 af[4];
                #pragma unroll
                for (int mt = 0; mt < 4; ++mt)
                    af[mt] = *reinterpret_cast<const bf16x8*>(
                        &uet[(mt * 16 + l16) * 136 + kk * 32 + quad * 8]);
                #pragma unroll
                for (int mt = 0; mt < 4; ++mt)
                    #pragma unroll
                    for (int nt = 0; nt < 2; ++nt)
                        acc1[mt][nt] = __builtin_amdgcn_mfma_f32_16x16x32_bf16(
                            bc[nt], af[mt], acc1[mt][nt], 0, 0, 0);
                bc[0] = bn[0]; bc[1] = bn[1];
            }
            if (nc == 0) {   // issue-early: nc=1 L1 B (in flight through L2)
                bc[0] = *reinterpret_cast<const bf16x8*>(tw1ue_base + 32768);
                bc[1] = *reinterpret_cast<const bf16x8*>(tw1ue_base + 32768 + 2048);
            }
            #pragma unroll
            for (int mt = 0; mt < 4; ++mt)
                #pragma unroll
                for (int nt = 0; nt < 2; ++nt) {
                    ushort4 o = pack4(fmaxf(acc1[mt][nt][0], 0.f),
                                      fmaxf(acc1[mt][nt][1], 0.f),
                                      fmaxf(acc1[mt][nt][2], 0.f),
                                      fmaxf(acc1[mt][nt][3], 0.f));
                    *reinterpret_cast<ushort4*>(
                        &h1t[(mt * 16 + l16) * 264 + wv * 32 + nt * 16 + quad * 4]) = o;
                }
        }
        __syncthreads();
        {
            #pragma unroll
            for (int k2 = 0; k2 < 8; ++k2) {
                if (k2 < 7) {
                    cn[0] = *reinterpret_cast<const bf16x8*>(cb + (k2 + 1) * 32);
                    cn[1] = *reinterpret_cast<const bf16x8*>(cb + 8192 + (k2 + 1) * 32);
                }
                bf16x8 af[4];
                #pragma unroll
                for (int mt = 0; mt < 4; ++mt)
                    af[mt] = *reinterpret_cast<const bf16x8*>(
                        &h1t[(mt * 16 + l16) * 264 + k2 * 32 + quad * 8]);
                #pragma unroll
                for (int mt = 0; mt < 4; ++mt)
                    #pragma unroll
                    for (int nt = 0; nt < 2; ++nt)
                        acc2[mt][nt] = __builtin_amdgcn_mfma_f32_16x16x32_bf16(
                            cc[nt], af[mt], acc2[mt][nt], 0, 0, 0);
                cc[0] = cn[0]; cc[1] = cn[1];
            }
        }
        if (nc == 0) __syncthreads();
    }
    __syncthreads();                             // last h1t read done

    // ---- heads: in-register from acc2 (fp32 t, no bf16 round) ----
    {
        float svr[4] = {0.f, 0.f, 0.f, 0.f};
        float sdr[4] = {0.f, 0.f, 0.f, 0.f};
        #pragma unroll
        for (int nt = 0; nt < 2; ++nt) {
            float4 vw4 = *reinterpret_cast<const float4*>(
                &vw[wv * 32 + nt * 16 + quad * 4]);
            float4 dw4 = *reinterpret_cast<const float4*>(
                &dw[wv * 32 + nt * 16 + quad * 4]);
            #pragma unroll
            for (int mt = 0; mt < 4; ++mt) {
                float t0 = fmaxf(acc2[mt][nt][0], 0.f);
                float t1 = fmaxf(acc2[mt][nt][1], 0.f);
                float t2 = fmaxf(acc2[mt][nt][2], 0.f);
                float t3 = fmaxf(acc2[mt][nt][3], 0.f);
                svr[mt] += t0 * vw4.x + t1 * vw4.y + t2 * vw4.z + t3 * vw4.w;
                sdr[mt] += t0 * dw4.x + t1 * dw4.y + t2 * dw4.z + t3 * dw4.w;
            }
        }
        #pragma unroll
        for (int mt = 0; mt < 4; ++mt) {         // reduce over quads
            svr[mt] += __shfl_xor(svr[mt], 16);
            svr[mt] += __shfl_xor(svr[mt], 32);
            sdr[mt] += __shfl_xor(sdr[mt], 16);
            sdr[mt] += __shfl_xor(sdr[mt], 32);
        }
        if (quad == 0) {                         // stage per-wave partials
            #pragma unroll
            for (int mt = 0; mt < 4; ++mt) {
                int row = mt * 16 + l16;
                hred[(row * 2 + 0) * 8 + wv] = svr[mt];
                hred[(row * 2 + 1) * 8 + wv] = sdr[mt];
            }
        }
    }
    __syncthreads();
    if (t < 128) {                               // final reduce over 8 waves
        const float* p = &hred[t * 8];
        float s = p[0] + p[1] + p[2] + p[3] + p[4] + p[5] + p[6] + p[7];
        int row = t >> 1;
        int g = blockIdx.x * 64 + row;
        if ((t & 1) == 0) {
            out[g] = s + vb[0];
        } else {
            float z = s + db[0];
            float sig = 1.f / (1.f + __expf(-z));
            out[B_ * 16 + g] = sig * 0.4f + 0.1f;
        }
    }
}

extern "C" void kernel_launch(void* const* d_in, const int* in_sizes, int n_in,
                              void* d_out, int out_size, void* d_ws, size_t ws_size,
                              hipStream_t stream) {
    const float* obs = (const float*)d_in[0];
    const float* sw1 = (const float*)d_in[1];
    const float* sb1 = (const float*)d_in[2];
    const float* sw2 = (const float*)d_in[3];
    const float* sb2 = (const float*)d_in[4];
    const float* uw1 = (const float*)d_in[5];
    const float* ub1 = (const float*)d_in[6];
    const float* uw2 = (const float*)d_in[7];
    const float* ub2 = (const float*)d_in[8];
    const float* emb = (const float*)d_in[9];
    const float* tw1 = (const float*)d_in[10];
    const float* tb1 = (const float*)d_in[11];
    const float* tw2 = (const float*)d_in[12];
    const float* tb2 = (const float*)d_in[13];
    const float* vw  = (const float*)d_in[14];
    const float* vb  = (const float*)d_in[15];
    const float* dw  = (const float*)d_in[16];
    const float* db  = (const float*)d_in[17];

    uint16_t* wsb = (uint16_t*)d_ws;

    k_conv<<<404, 256, 0, stream>>>(tw1, tw2, uw2, sw2, uw1, wsb);
    k_cse<<<512, 512, 0, stream>>>(obs, sw1, sb1, sb2, tb1, wsb);
    k_main<<<B_ / 4, 512, 0, stream>>>(obs, ub1, ub2, emb, tb2,
                                       vw, vb, dw, db, wsb, (float*)d_out);
}